// Round 1
// baseline (8501.619 us; speedup 1.0000x reference)
//
#include <hip/hip_runtime.h>
#include <hip/hip_bf16.h>

// AttentiveFuturecaster: fused GRU-encoder + attentive GRU-decoder + FC head.
// Round 3: occupancy push. BT_ 16 -> 4: grid 128 -> 512 blocks, LDS 125KB ->
// ~43KB/block => 2 independent blocks/CU (16 waves/CU, 4 waves/SIMD) on all
// 256 CUs, vs 1 block/CU on 128 CUs before. The two co-resident blocks have
// desynchronized barriers, hiding the per-step L2 weight-reload and decoder
// hs-load latencies that dominated (MfmaUtil 4.8 / VALU 10.4 / HBM 12.7%).
// MFMA tiles now carry 4 valid rows of 16 (A rows 4..15 alias rows 0..3 via
// l16&3; duplicate D rows never read); elementwise is exec-masked to quad 0.
// Numerics identical to round 2 (split-bf16 hi+lo A, fp32-carried state).
// ws layout: [0, 128MB): hs bf16 [B,T,H]; then 1MB bf16 weight blob.

#define B_    2048
#define T_    128
#define F_    64
#define H_    256
#define OUT_  32
#define BT_   4
#define NTH_  512
#define NB_   (B_ / BT_)
#define HSTR_ 264   // bf16 h-tile LDS row stride
#define FSTR_ 260   // fp32 h-tile LDS row stride
#define XSTR_ 72    // bf16 x-tile LDS row stride
#define SSTR_ 260   // fp32 scratch row stride (softmax w / fc1 out)

// bf16 weight blob element offsets inside ws (after hs)
#define W_EIH_  0
#define W_EHH_  (W_EIH_ + 3 * H_ * F_)     // 49152
#define W_DHH_  (W_EHH_ + 3 * H_ * H_)     // 245760
#define W_F1_   (W_DHH_ + 3 * H_ * H_)     // 442368
#define W_TOT_  (W_F1_ + H_ * H_)          // 507904

typedef __attribute__((ext_vector_type(8))) short bf16x8;
typedef __attribute__((ext_vector_type(4))) float f32x4;

__device__ __forceinline__ f32x4 mfma16(bf16x8 a, bf16x8 b, f32x4 c) {
  return __builtin_amdgcn_mfma_f32_16x16x32_bf16(a, b, c, 0, 0, 0);
}
__device__ __forceinline__ float sigm_(float x) { return 1.0f / (1.0f + __expf(-x)); }
__device__ __forceinline__ float tanh_(float x) {
  x = fminf(15.0f, fmaxf(-15.0f, x));
  float e = __expf(2.0f * x);
  return (e - 1.0f) / (e + 1.0f);
}

__global__ __launch_bounds__(256) void af_convert_weights(
    const float* __restrict__ eWih, const float* __restrict__ eWhh,
    const float* __restrict__ dWhh, const float* __restrict__ f1W,
    __hip_bfloat16* __restrict__ wb) {
  for (int i = blockIdx.x * blockDim.x + threadIdx.x; i < W_TOT_;
       i += gridDim.x * blockDim.x) {
    float v;
    if (i < W_EHH_)      v = eWih[i - W_EIH_];
    else if (i < W_DHH_) v = eWhh[i - W_EHH_];
    else if (i < W_F1_)  v = dWhh[i - W_DHH_];
    else                 v = f1W[i - W_F1_];
    wb[i] = __float2bfloat16(v);
  }
}

__global__ __launch_bounds__(NTH_, 4) void af_fused_kernel(
    const float* __restrict__ x,
    const float* __restrict__ h0,
    const float* __restrict__ ebih,
    const float* __restrict__ ebhh,
    const float* __restrict__ dWih,
    const float* __restrict__ dbih,
    const float* __restrict__ dbhh,
    const float* __restrict__ aWq,
    const float* __restrict__ abq,
    const float* __restrict__ f1b,
    const float* __restrict__ f2W,
    const float* __restrict__ f2b,
    const __hip_bfloat16* __restrict__ eWihB,
    const __hip_bfloat16* __restrict__ eWhhB,
    const __hip_bfloat16* __restrict__ dWhhB,
    const __hip_bfloat16* __restrict__ f1WB,
    __hip_bfloat16* __restrict__ hs,     // [B,T,H] bf16 (workspace)
    float* __restrict__ dout)            // [B,OUT] fp32
{
  __shared__ __hip_bfloat16 sh_h[2][BT_ * HSTR_];   // h hi (bf16)
  __shared__ __hip_bfloat16 sh_l[2][BT_ * HSTR_];   // h lo (bf16 residual)
  __shared__ float          s_hf[2][BT_ * FSTR_];   // h fp32 (carried state)
  __shared__ __hip_bfloat16 sh_x[2][BT_ * XSTR_];   // x hi
  __shared__ __hip_bfloat16 sh_xl[2][BT_ * XSTR_];  // x lo
  __shared__ float s_A[BT_ * T_], s_C[BT_ * T_];    // rank-1 attention tables
  __shared__ float s_ebr[H_], s_ebz[H_], s_ebin[H_], s_ebhn[H_];
  __shared__ float s_dbr[H_], s_dbz[H_], s_dbin[H_], s_dbhn[H_];
  __shared__ float s_dwih[3 * H_];
  __shared__ float s_wq[H_], s_bq[H_], s_f1b[H_], s_f2w[H_];
  __shared__ float s_f2b;
  __shared__ float s_prev[BT_];
  __shared__ float s_scr[BT_ * SSTR_];  // softmax w (cols 0..127) / fc1 out (cols 0..255)

  const int tid  = threadIdx.x;
  const int b0   = blockIdx.x * BT_;
  const int lane = tid & 63;
  const int wid  = tid >> 6;     // 0..7
  const int quad = lane >> 4;    // 0..3
  const int l16  = lane & 15;    // 0..15
  const int arow = l16 & 3;      // A-operand row alias (4 valid batch rows)
  const int mg   = tid >> 6;     // 0..7: batch row group (active when < BT_)
  const int cg   = tid & 63;     // 0..63: position within 64-lane row group

  // ---------------- prologue: constants + h0 + x(t=0) into LDS ----------------
  for (int g = tid; g < H_; g += NTH_) {
    s_ebr[g]  = ebih[g]          + ebhh[g];
    s_ebz[g]  = ebih[H_ + g]     + ebhh[H_ + g];
    s_ebin[g] = ebih[2 * H_ + g];
    s_ebhn[g] = ebhh[2 * H_ + g];
    s_dbr[g]  = dbih[g]          + dbhh[g];
    s_dbz[g]  = dbih[H_ + g]     + dbhh[H_ + g];
    s_dbin[g] = dbih[2 * H_ + g];
    s_dbhn[g] = dbhh[2 * H_ + g];
    s_wq[g]   = aWq[g];
    s_bq[g]   = abq[g];
    s_f1b[g]  = f1b[g];
    s_f2w[g]  = f2W[g];
  }
  for (int g = tid; g < 3 * H_; g += NTH_) s_dwih[g] = dWih[g];
  if (tid == 0) s_f2b = f2b[0];

  if (mg < BT_) {
    const float* hp = h0 + (size_t)(b0 + mg) * H_ + cg * 4;
    float4 v0 = *(const float4*)(hp);
    float vv[4] = {v0.x, v0.y, v0.z, v0.w};
#pragma unroll
    for (int j = 0; j < 4; ++j) {
      float v = vv[j];
      s_hf[0][mg * FSTR_ + cg * 4 + j] = v;
      __hip_bfloat16 hi = __float2bfloat16(v);
      sh_h[0][mg * HSTR_ + cg * 4 + j] = hi;
      sh_l[0][mg * HSTR_ + cg * 4 + j] = __float2bfloat16(v - __bfloat162float(hi));
    }
    float xv = x[((size_t)(b0 + mg) * T_) * F_ + cg];
    __hip_bfloat16 xh = __float2bfloat16(xv);
    sh_x[0][mg * XSTR_ + cg]  = xh;
    sh_xl[0][mg * XSTR_ + cg] = __float2bfloat16(xv - __bfloat162float(xh));
  }
  __syncthreads();

  // ============================ ENCODER: 128 GRU steps ============================
  int cur = 0;
  for (int t = 0; t < T_; ++t) {
    const int nxt = cur ^ 1;
    bf16x8 ah[8], al[8], ax[2], axl[2];
#pragma unroll
    for (int kk = 0; kk < 8; ++kk) {
      ah[kk] = *(const bf16x8*)&sh_h[cur][arow * HSTR_ + kk * 32 + quad * 8];
      al[kk] = *(const bf16x8*)&sh_l[cur][arow * HSTR_ + kk * 32 + quad * 8];
    }
#pragma unroll
    for (int kk = 0; kk < 2; ++kk) {
      ax[kk]  = *(const bf16x8*)&sh_x[cur][arow * XSTR_ + kk * 32 + quad * 8];
      axl[kk] = *(const bf16x8*)&sh_xl[cur][arow * XSTR_ + kk * 32 + quad * 8];
    }

#pragma unroll
    for (int s2 = 0; s2 < 2; ++s2) {
      const int c = 2 * wid + s2;       // h-column block 0..15
      const int g = 16 * c + l16;       // gate column 0..255
      const __hip_bfloat16* pr = eWhhB + (size_t)g * H_ + quad * 8;
      const __hip_bfloat16* pz = eWhhB + (size_t)(H_ + g) * H_ + quad * 8;
      const __hip_bfloat16* pn = eWhhB + (size_t)(2 * H_ + g) * H_ + quad * 8;
      f32x4 ar = {0.f, 0.f, 0.f, 0.f}, az = ar, ani = ar, anh = ar;
#pragma unroll
      for (int kk = 0; kk < 8; ++kk) {
        bf16x8 br = *(const bf16x8*)(pr + kk * 32);
        bf16x8 bz = *(const bf16x8*)(pz + kk * 32);
        bf16x8 bn = *(const bf16x8*)(pn + kk * 32);
        ar  = mfma16(al[kk], br, ar);  ar  = mfma16(ah[kk], br, ar);
        az  = mfma16(al[kk], bz, az);  az  = mfma16(ah[kk], bz, az);
        anh = mfma16(al[kk], bn, anh); anh = mfma16(ah[kk], bn, anh);
      }
      const __hip_bfloat16* qr = eWihB + (size_t)g * F_ + quad * 8;
      const __hip_bfloat16* qz = eWihB + (size_t)(H_ + g) * F_ + quad * 8;
      const __hip_bfloat16* qn = eWihB + (size_t)(2 * H_ + g) * F_ + quad * 8;
#pragma unroll
      for (int kk = 0; kk < 2; ++kk) {
        bf16x8 br = *(const bf16x8*)(qr + kk * 32);
        bf16x8 bz = *(const bf16x8*)(qz + kk * 32);
        bf16x8 bn = *(const bf16x8*)(qn + kk * 32);
        ar  = mfma16(axl[kk], br, ar);  ar  = mfma16(ax[kk], br, ar);
        az  = mfma16(axl[kk], bz, az);  az  = mfma16(ax[kk], bz, az);
        ani = mfma16(axl[kk], bn, ani); ani = mfma16(ax[kk], bn, ani);
      }
      const float br_ = s_ebr[g], bz_ = s_ebz[g], bin_ = s_ebin[g], bhn_ = s_ebhn[g];
      if (quad == 0) {
#pragma unroll
        for (int i = 0; i < 4; ++i) {
          const int m = i;              // D row = batch (quad==0 -> rows 0..3)
          float r = sigm_(ar[i] + br_);
          float z = sigm_(az[i] + bz_);
          float n = tanh_(ani[i] + bin_ + r * (anh[i] + bhn_));
          float hold = s_hf[cur][m * FSTR_ + g];
          float hn = (1.0f - z) * n + z * hold;
          s_hf[nxt][m * FSTR_ + g] = hn;
          __hip_bfloat16 hi = __float2bfloat16(hn);
          sh_h[nxt][m * HSTR_ + g] = hi;
          sh_l[nxt][m * HSTR_ + g] = __float2bfloat16(hn - __bfloat162float(hi));
        }
      }
    }
    __syncthreads();

    // output phase: hs store (bf16 hi), A/C dots (fp32), x prefetch (t+1)
    if (mg < BT_) {
      uint2 hv = *(const uint2*)&sh_h[nxt][mg * HSTR_ + cg * 4];
      *(uint2*)&hs[((size_t)(b0 + mg) * T_ + t) * H_ + cg * 4] = hv;
      const float* hp = &s_hf[nxt][mg * FSTR_ + cg * 4];
      float pa = 0.f, pc = 0.f;
#pragma unroll
      for (int j = 0; j < 4; ++j) {
        float hvf = hp[j];
        pa += hvf * s_wq[cg * 4 + j];
        pc += hvf * s_bq[cg * 4 + j];
      }
#pragma unroll
      for (int off = 32; off >= 1; off >>= 1) {
        pa += __shfl_xor(pa, off, 64);
        pc += __shfl_xor(pc, off, 64);
      }
      if (cg == 0) {
        s_A[mg * T_ + t] = pa;
        s_C[mg * T_ + t] = pc;
      }
      if (t + 1 < T_) {
        float xv = x[((size_t)(b0 + mg) * T_ + (t + 1)) * F_ + cg];
        __hip_bfloat16 xh = __float2bfloat16(xv);
        sh_x[nxt][mg * XSTR_ + cg]  = xh;
        sh_xl[nxt][mg * XSTR_ + cg] = __float2bfloat16(xv - __bfloat162float(xh));
      }
    }
    __syncthreads();
    cur = nxt;
  }

  // ============================ DECODER: 32 steps ============================
  if (tid < BT_)
    s_prev[tid] = x[((size_t)(b0 + tid) * T_ + (T_ - 1)) * F_];
  __syncthreads();

  for (int s = 0; s < OUT_; ++s) {
    // P1: scores = (prev*A + C)*scale, softmax over T per batch row -> s_scr
    if (mg < BT_) {
      float2 a2 = *(const float2*)(s_A + mg * T_ + cg * 2);
      float2 c2 = *(const float2*)(s_C + mg * T_ + cg * 2);
      const float pv = s_prev[mg];
      float sc0 = (pv * a2.x + c2.x) * 0.0625f;
      float sc1 = (pv * a2.y + c2.y) * 0.0625f;
      float mx = fmaxf(sc0, sc1);
#pragma unroll
      for (int off = 32; off >= 1; off >>= 1) mx = fmaxf(mx, __shfl_xor(mx, off, 64));
      float e0 = __expf(sc0 - mx), e1 = __expf(sc1 - mx);
      float ss = e0 + e1;
#pragma unroll
      for (int off = 32; off >= 1; off >>= 1) ss += __shfl_xor(ss, off, 64);
      const float inv = 1.0f / ss;
      *(float2*)&s_scr[mg * SSTR_ + cg * 2] = make_float2(e0 * inv, e1 * inv);
    }
    __syncthreads();

    // P2: ctx[m,h] = sum_t w[m,t] * hs[m,t,h]  (fp32 VALU, bf16 loads)
    if (mg < BT_) {
      float acc[4] = {0.f, 0.f, 0.f, 0.f};
      const __hip_bfloat16* hp = hs + (size_t)(b0 + mg) * T_ * H_ + cg * 4;
      const float* wp = &s_scr[mg * SSTR_];
#pragma unroll 4
      for (int t = 0; t < T_; ++t) {
        uint2 hv = *(const uint2*)(hp + (size_t)t * H_);
        const float wt = wp[t];
        acc[0] = fmaf(wt, __uint_as_float(hv.x << 16),         acc[0]);
        acc[1] = fmaf(wt, __uint_as_float(hv.x & 0xFFFF0000u), acc[1]);
        acc[2] = fmaf(wt, __uint_as_float(hv.y << 16),         acc[2]);
        acc[3] = fmaf(wt, __uint_as_float(hv.y & 0xFFFF0000u), acc[3]);
      }
#pragma unroll
      for (int j = 0; j < 4; ++j) {
        float v = acc[j];
        s_hf[0][mg * FSTR_ + cg * 4 + j] = v;
        __hip_bfloat16 hi = __float2bfloat16(v);
        sh_h[0][mg * HSTR_ + cg * 4 + j] = hi;
        sh_l[0][mg * HSTR_ + cg * 4 + j] = __float2bfloat16(v - __bfloat162float(hi));
      }
    }
    __syncthreads();

    // P3: decoder GRU: gh = ctx @ dWhh^T (MFMA, split); gi = prev*dWih + b
    {
      bf16x8 ah2[8], al2[8];
#pragma unroll
      for (int kk = 0; kk < 8; ++kk) {
        ah2[kk] = *(const bf16x8*)&sh_h[0][arow * HSTR_ + kk * 32 + quad * 8];
        al2[kk] = *(const bf16x8*)&sh_l[0][arow * HSTR_ + kk * 32 + quad * 8];
      }
#pragma unroll
      for (int s2 = 0; s2 < 2; ++s2) {
        const int c = 2 * wid + s2;
        const int g = 16 * c + l16;
        const __hip_bfloat16* pr = dWhhB + (size_t)g * H_ + quad * 8;
        const __hip_bfloat16* pz = dWhhB + (size_t)(H_ + g) * H_ + quad * 8;
        const __hip_bfloat16* pn = dWhhB + (size_t)(2 * H_ + g) * H_ + quad * 8;
        f32x4 ar = {0.f, 0.f, 0.f, 0.f}, az = ar, anh = ar;
#pragma unroll
        for (int kk = 0; kk < 8; ++kk) {
          bf16x8 br = *(const bf16x8*)(pr + kk * 32);
          bf16x8 bz = *(const bf16x8*)(pz + kk * 32);
          bf16x8 bn = *(const bf16x8*)(pn + kk * 32);
          ar  = mfma16(al2[kk], br, ar);  ar  = mfma16(ah2[kk], br, ar);
          az  = mfma16(al2[kk], bz, az);  az  = mfma16(ah2[kk], bz, az);
          anh = mfma16(al2[kk], bn, anh); anh = mfma16(ah2[kk], bn, anh);
        }
        const float dr = s_dbr[g], dz = s_dbz[g], din = s_dbin[g], dhn = s_dbhn[g];
        const float wir = s_dwih[g], wiz = s_dwih[H_ + g], win = s_dwih[2 * H_ + g];
        if (quad == 0) {
#pragma unroll
          for (int i = 0; i < 4; ++i) {
            const int m = i;
            const float pv = s_prev[m];
            float r = sigm_(ar[i] + pv * wir + dr);
            float z = sigm_(az[i] + pv * wiz + dz);
            float n = tanh_(pv * win + din + r * (anh[i] + dhn));
            float ctxv = s_hf[0][m * FSTR_ + g];
            float hd = (1.0f - z) * n + z * ctxv;
            __hip_bfloat16 hi = __float2bfloat16(hd);
            sh_h[1][m * HSTR_ + g] = hi;
            sh_l[1][m * HSTR_ + g] = __float2bfloat16(hd - __bfloat162float(hi));
          }
        }
      }
    }
    __syncthreads();

    // P4: fc1 + relu (MFMA, split) -> fp32 in s_scr
    {
      bf16x8 ad[8], adl[8];
#pragma unroll
      for (int kk = 0; kk < 8; ++kk) {
        ad[kk]  = *(const bf16x8*)&sh_h[1][arow * HSTR_ + kk * 32 + quad * 8];
        adl[kk] = *(const bf16x8*)&sh_l[1][arow * HSTR_ + kk * 32 + quad * 8];
      }
#pragma unroll
      for (int s2 = 0; s2 < 2; ++s2) {
        const int c = 2 * wid + s2;
        const int j = 16 * c + l16;
        const __hip_bfloat16* pw = f1WB + (size_t)j * H_ + quad * 8;
        f32x4 a1 = {0.f, 0.f, 0.f, 0.f};
#pragma unroll
        for (int kk = 0; kk < 8; ++kk) {
          bf16x8 bw = *(const bf16x8*)(pw + kk * 32);
          a1 = mfma16(adl[kk], bw, a1);
          a1 = mfma16(ad[kk],  bw, a1);
        }
        const float bj = s_f1b[j];
        if (quad == 0) {
#pragma unroll
          for (int i = 0; i < 4; ++i) {
            const int m = i;
            s_scr[m * SSTR_ + j] = fmaxf(a1[i] + bj, 0.0f);
          }
        }
      }
    }
    __syncthreads();

    // P5: fc2 (fp32 dot) -> out, update prev
    if (mg < BT_) {
      const float* ap = &s_scr[mg * SSTR_ + cg * 4];
      float p = 0.f;
#pragma unroll
      for (int j = 0; j < 4; ++j)
        p += ap[j] * s_f2w[cg * 4 + j];
#pragma unroll
      for (int off = 32; off >= 1; off >>= 1) p += __shfl_xor(p, off, 64);
      if (cg == 0) {
        float o = p + s_f2b;
        s_prev[mg] = o;
        dout[(size_t)(b0 + mg) * OUT_ + s] = o;
      }
    }
    __syncthreads();
  }
}

extern "C" void kernel_launch(void* const* d_in, const int* in_sizes, int n_in,
                              void* d_out, int out_size, void* d_ws, size_t ws_size,
                              hipStream_t stream) {
  (void)in_sizes; (void)n_in; (void)out_size; (void)ws_size;
  const float* x    = (const float*)d_in[0];
  const float* h0   = (const float*)d_in[1];
  const float* eWih = (const float*)d_in[2];
  const float* eWhh = (const float*)d_in[3];
  const float* ebih = (const float*)d_in[4];
  const float* ebhh = (const float*)d_in[5];
  const float* dWih = (const float*)d_in[6];
  const float* dWhh = (const float*)d_in[7];
  const float* dbih = (const float*)d_in[8];
  const float* dbhh = (const float*)d_in[9];
  const float* aWq  = (const float*)d_in[10];
  const float* abq  = (const float*)d_in[11];
  const float* f1W  = (const float*)d_in[12];
  const float* f1b  = (const float*)d_in[13];
  const float* f2W  = (const float*)d_in[14];
  const float* f2b  = (const float*)d_in[15];

  __hip_bfloat16* hs = (__hip_bfloat16*)d_ws;   // 134,217,728 B
  __hip_bfloat16* wb = (__hip_bfloat16*)((char*)d_ws + (size_t)B_ * T_ * H_ * 2);

  hipLaunchKernelGGL(af_convert_weights, dim3(256), dim3(256), 0, stream,
                     eWih, eWhh, dWhh, f1W, wb);
  hipLaunchKernelGGL(af_fused_kernel, dim3(NB_), dim3(NTH_), 0, stream,
                     x, h0, ebih, ebhh, dWih, dbih, dbhh, aWq, abq, f1b, f2W, f2b,
                     wb + W_EIH_, wb + W_EHH_, wb + W_DHH_, wb + W_F1_,
                     hs, (float*)d_out);
}

// Round 2
// 3183.291 us; speedup vs baseline: 2.6707x; 2.6707x over previous
//
#include <hip/hip_runtime.h>
#include <hip/hip_bf16.h>

// AttentiveFuturecaster: fused GRU-encoder + attentive GRU-decoder + FC head.
// Round 4: back to BT=16 / grid=128 (round-2 cache behavior: weight stream
// demand is 64MB/step aggregate and L2/L3-resident; round 3's 512 blocks
// quadrupled it and thrashed to HBM, 3x regression). Within-block latency
// attack instead: NTH 512->1024, COLUMN-split — 16 waves each own ONE
// 16-column block (c=wid) instead of two, halving per-wave loads/MFMAs and
// doubling waves/SIMD (2->4) at identical per-block weight traffic. No
// cross-wave reduction, still 2 barriers/step. s_hf and sh_x single-buffered
// (hazard-checked) -> LDS ~101KB. __launch_bounds__(1024,4) caps VGPR at 128
// (round 2 compiled at exactly 128 with the same per-wave register content).
// ws layout: [0, 128MB): hs bf16 [B,T,H]; then 1MB bf16 weight blob.

#define B_    2048
#define T_    128
#define F_    64
#define H_    256
#define OUT_  32
#define BT_   16
#define NTH_  1024
#define NB_   (B_ / BT_)
#define HSTR_ 264   // bf16 h-tile LDS row stride
#define FSTR_ 260   // fp32 h-tile LDS row stride
#define XSTR_ 72    // bf16 x-tile LDS row stride
#define SSTR_ 260   // fp32 scratch row stride (softmax w / fc1 out)

// bf16 weight blob element offsets inside ws (after hs)
#define W_EIH_  0
#define W_EHH_  (W_EIH_ + 3 * H_ * F_)     // 49152
#define W_DHH_  (W_EHH_ + 3 * H_ * H_)     // 245760
#define W_F1_   (W_DHH_ + 3 * H_ * H_)     // 442368
#define W_TOT_  (W_F1_ + H_ * H_)          // 507904

typedef __attribute__((ext_vector_type(8))) short bf16x8;
typedef __attribute__((ext_vector_type(4))) float f32x4;

__device__ __forceinline__ f32x4 mfma16(bf16x8 a, bf16x8 b, f32x4 c) {
  return __builtin_amdgcn_mfma_f32_16x16x32_bf16(a, b, c, 0, 0, 0);
}
__device__ __forceinline__ float sigm_(float x) { return 1.0f / (1.0f + __expf(-x)); }
__device__ __forceinline__ float tanh_(float x) {
  x = fminf(15.0f, fmaxf(-15.0f, x));
  float e = __expf(2.0f * x);
  return (e - 1.0f) / (e + 1.0f);
}

__global__ __launch_bounds__(256) void af_convert_weights(
    const float* __restrict__ eWih, const float* __restrict__ eWhh,
    const float* __restrict__ dWhh, const float* __restrict__ f1W,
    __hip_bfloat16* __restrict__ wb) {
  for (int i = blockIdx.x * blockDim.x + threadIdx.x; i < W_TOT_;
       i += gridDim.x * blockDim.x) {
    float v;
    if (i < W_EHH_)      v = eWih[i - W_EIH_];
    else if (i < W_DHH_) v = eWhh[i - W_EHH_];
    else if (i < W_F1_)  v = dWhh[i - W_DHH_];
    else                 v = f1W[i - W_F1_];
    wb[i] = __float2bfloat16(v);
  }
}

__global__ __launch_bounds__(NTH_, 4) void af_fused_kernel(
    const float* __restrict__ x,
    const float* __restrict__ h0,
    const float* __restrict__ ebih,
    const float* __restrict__ ebhh,
    const float* __restrict__ dWih,
    const float* __restrict__ dbih,
    const float* __restrict__ dbhh,
    const float* __restrict__ aWq,
    const float* __restrict__ abq,
    const float* __restrict__ f1b,
    const float* __restrict__ f2W,
    const float* __restrict__ f2b,
    const __hip_bfloat16* __restrict__ eWihB,
    const __hip_bfloat16* __restrict__ eWhhB,
    const __hip_bfloat16* __restrict__ dWhhB,
    const __hip_bfloat16* __restrict__ f1WB,
    __hip_bfloat16* __restrict__ hs,     // [B,T,H] bf16 (workspace)
    float* __restrict__ dout)            // [B,OUT] fp32
{
  __shared__ __hip_bfloat16 sh_h[2][BT_ * HSTR_];   // h hi (bf16), double-buffered
  __shared__ __hip_bfloat16 sh_l[2][BT_ * HSTR_];   // h lo (bf16 residual)
  __shared__ float          s_hf[BT_ * FSTR_];      // h fp32 (carried state), single
  __shared__ __hip_bfloat16 sh_x[BT_ * XSTR_];      // x hi, single (write-after-reads)
  __shared__ __hip_bfloat16 sh_xl[BT_ * XSTR_];     // x lo
  __shared__ float s_A[BT_ * T_], s_C[BT_ * T_];    // rank-1 attention tables
  __shared__ float s_ebr[H_], s_ebz[H_], s_ebin[H_], s_ebhn[H_];
  __shared__ float s_dbr[H_], s_dbz[H_], s_dbin[H_], s_dbhn[H_];
  __shared__ float s_dwih[3 * H_];
  __shared__ float s_wq[H_], s_bq[H_], s_f1b[H_], s_f2w[H_];
  __shared__ float s_f2b;
  __shared__ float s_prev[BT_];
  __shared__ float s_scr[BT_ * SSTR_];  // softmax w (cols 0..127) / fc1 out (cols 0..255)

  const int tid  = threadIdx.x;
  const int b0   = blockIdx.x * BT_;
  const int lane = tid & 63;
  const int wid  = tid >> 6;     // 0..15: wave = column block c
  const int quad = lane >> 4;    // 0..3
  const int l16  = lane & 15;    // 0..15
  const int mg   = tid >> 6;     // 0..15: batch row for row-parallel phases
  const int cg   = tid & 63;     // 0..63: position within 64-lane row group

  // ---------------- prologue: constants + h0 + x(t=0) into LDS ----------------
  for (int g = tid; g < H_; g += NTH_) {
    s_ebr[g]  = ebih[g]          + ebhh[g];
    s_ebz[g]  = ebih[H_ + g]     + ebhh[H_ + g];
    s_ebin[g] = ebih[2 * H_ + g];
    s_ebhn[g] = ebhh[2 * H_ + g];
    s_dbr[g]  = dbih[g]          + dbhh[g];
    s_dbz[g]  = dbih[H_ + g]     + dbhh[H_ + g];
    s_dbin[g] = dbih[2 * H_ + g];
    s_dbhn[g] = dbhh[2 * H_ + g];
    s_wq[g]   = aWq[g];
    s_bq[g]   = abq[g];
    s_f1b[g]  = f1b[g];
    s_f2w[g]  = f2W[g];
  }
  for (int g = tid; g < 3 * H_; g += NTH_) s_dwih[g] = dWih[g];
  if (tid == 0) s_f2b = f2b[0];

  {
    const float* hp = h0 + (size_t)(b0 + mg) * H_ + cg * 4;
    float4 v0 = *(const float4*)(hp);
    float vv[4] = {v0.x, v0.y, v0.z, v0.w};
#pragma unroll
    for (int j = 0; j < 4; ++j) {
      float v = vv[j];
      s_hf[mg * FSTR_ + cg * 4 + j] = v;
      __hip_bfloat16 hi = __float2bfloat16(v);
      sh_h[0][mg * HSTR_ + cg * 4 + j] = hi;
      sh_l[0][mg * HSTR_ + cg * 4 + j] = __float2bfloat16(v - __bfloat162float(hi));
    }
    float xv = x[((size_t)(b0 + mg) * T_) * F_ + cg];
    __hip_bfloat16 xh = __float2bfloat16(xv);
    sh_x[mg * XSTR_ + cg]  = xh;
    sh_xl[mg * XSTR_ + cg] = __float2bfloat16(xv - __bfloat162float(xh));
  }
  __syncthreads();

  // ============================ ENCODER: 128 GRU steps ============================
  int cur = 0;
  for (int t = 0; t < T_; ++t) {
    const int nxt = cur ^ 1;
    bf16x8 ah[8], al[8], ax[2], axl[2];
#pragma unroll
    for (int kk = 0; kk < 8; ++kk) {
      ah[kk] = *(const bf16x8*)&sh_h[cur][l16 * HSTR_ + kk * 32 + quad * 8];
      al[kk] = *(const bf16x8*)&sh_l[cur][l16 * HSTR_ + kk * 32 + quad * 8];
    }
#pragma unroll
    for (int kk = 0; kk < 2; ++kk) {
      ax[kk]  = *(const bf16x8*)&sh_x[l16 * XSTR_ + kk * 32 + quad * 8];
      axl[kk] = *(const bf16x8*)&sh_xl[l16 * XSTR_ + kk * 32 + quad * 8];
    }

    {
      const int g = 16 * wid + l16;     // gate column 0..255 (one c per wave)
      const __hip_bfloat16* pr = eWhhB + (size_t)g * H_ + quad * 8;
      const __hip_bfloat16* pz = eWhhB + (size_t)(H_ + g) * H_ + quad * 8;
      const __hip_bfloat16* pn = eWhhB + (size_t)(2 * H_ + g) * H_ + quad * 8;
      f32x4 ar = {0.f, 0.f, 0.f, 0.f}, az = ar, ani = ar, anh = ar;
#pragma unroll
      for (int kk = 0; kk < 8; ++kk) {
        bf16x8 br = *(const bf16x8*)(pr + kk * 32);
        bf16x8 bz = *(const bf16x8*)(pz + kk * 32);
        bf16x8 bn = *(const bf16x8*)(pn + kk * 32);
        ar  = mfma16(al[kk], br, ar);  ar  = mfma16(ah[kk], br, ar);
        az  = mfma16(al[kk], bz, az);  az  = mfma16(ah[kk], bz, az);
        anh = mfma16(al[kk], bn, anh); anh = mfma16(ah[kk], bn, anh);
      }
      const __hip_bfloat16* qr = eWihB + (size_t)g * F_ + quad * 8;
      const __hip_bfloat16* qz = eWihB + (size_t)(H_ + g) * F_ + quad * 8;
      const __hip_bfloat16* qn = eWihB + (size_t)(2 * H_ + g) * F_ + quad * 8;
#pragma unroll
      for (int kk = 0; kk < 2; ++kk) {
        bf16x8 br = *(const bf16x8*)(qr + kk * 32);
        bf16x8 bz = *(const bf16x8*)(qz + kk * 32);
        bf16x8 bn = *(const bf16x8*)(qn + kk * 32);
        ar  = mfma16(axl[kk], br, ar);  ar  = mfma16(ax[kk], br, ar);
        az  = mfma16(axl[kk], bz, az);  az  = mfma16(ax[kk], bz, az);
        ani = mfma16(axl[kk], bn, ani); ani = mfma16(ax[kk], bn, ani);
      }
      const float br_ = s_ebr[g], bz_ = s_ebz[g], bin_ = s_ebin[g], bhn_ = s_ebhn[g];
#pragma unroll
      for (int i = 0; i < 4; ++i) {
        const int m = quad * 4 + i;     // D row = batch
        float r = sigm_(ar[i] + br_);
        float z = sigm_(az[i] + bz_);
        float n = tanh_(ani[i] + bin_ + r * (anh[i] + bhn_));
        float hold = s_hf[m * FSTR_ + g];
        float hn = (1.0f - z) * n + z * hold;
        s_hf[m * FSTR_ + g] = hn;
        __hip_bfloat16 hi = __float2bfloat16(hn);
        sh_h[nxt][m * HSTR_ + g] = hi;
        sh_l[nxt][m * HSTR_ + g] = __float2bfloat16(hn - __bfloat162float(hi));
      }
    }
    __syncthreads();

    // output phase: hs store (bf16 hi), A/C dots (fp32), x prefetch (t+1)
    {
      uint2 hv = *(const uint2*)&sh_h[nxt][mg * HSTR_ + cg * 4];
      *(uint2*)&hs[((size_t)(b0 + mg) * T_ + t) * H_ + cg * 4] = hv;
      const float* hp = &s_hf[mg * FSTR_ + cg * 4];
      float pa = 0.f, pc = 0.f;
#pragma unroll
      for (int j = 0; j < 4; ++j) {
        float hvf = hp[j];
        pa += hvf * s_wq[cg * 4 + j];
        pc += hvf * s_bq[cg * 4 + j];
      }
#pragma unroll
      for (int off = 32; off >= 1; off >>= 1) {
        pa += __shfl_xor(pa, off, 64);
        pc += __shfl_xor(pc, off, 64);
      }
      if (cg == 0) {
        s_A[mg * T_ + t] = pa;
        s_C[mg * T_ + t] = pc;
      }
      if (t + 1 < T_) {
        float xv = x[((size_t)(b0 + mg) * T_ + (t + 1)) * F_ + cg];
        __hip_bfloat16 xh = __float2bfloat16(xv);
        sh_x[mg * XSTR_ + cg]  = xh;
        sh_xl[mg * XSTR_ + cg] = __float2bfloat16(xv - __bfloat162float(xh));
      }
    }
    __syncthreads();
    cur = nxt;
  }

  // ============================ DECODER: 32 steps ============================
  if (tid < BT_)
    s_prev[tid] = x[((size_t)(b0 + tid) * T_ + (T_ - 1)) * F_];
  __syncthreads();

  for (int s = 0; s < OUT_; ++s) {
    // P1: scores = (prev*A + C)*scale, softmax over T per batch row -> s_scr
    {
      float2 a2 = *(const float2*)(s_A + mg * T_ + cg * 2);
      float2 c2 = *(const float2*)(s_C + mg * T_ + cg * 2);
      const float pv = s_prev[mg];
      float sc0 = (pv * a2.x + c2.x) * 0.0625f;
      float sc1 = (pv * a2.y + c2.y) * 0.0625f;
      float mx = fmaxf(sc0, sc1);
#pragma unroll
      for (int off = 32; off >= 1; off >>= 1) mx = fmaxf(mx, __shfl_xor(mx, off, 64));
      float e0 = __expf(sc0 - mx), e1 = __expf(sc1 - mx);
      float ss = e0 + e1;
#pragma unroll
      for (int off = 32; off >= 1; off >>= 1) ss += __shfl_xor(ss, off, 64);
      const float inv = 1.0f / ss;
      *(float2*)&s_scr[mg * SSTR_ + cg * 2] = make_float2(e0 * inv, e1 * inv);
    }
    __syncthreads();

    // P2: ctx[m,h] = sum_t w[m,t] * hs[m,t,h]  (fp32 VALU, bf16 loads)
    {
      float acc[4] = {0.f, 0.f, 0.f, 0.f};
      const __hip_bfloat16* hp = hs + (size_t)(b0 + mg) * T_ * H_ + cg * 4;
      const float* wp = &s_scr[mg * SSTR_];
#pragma unroll 4
      for (int t = 0; t < T_; ++t) {
        uint2 hv = *(const uint2*)(hp + (size_t)t * H_);
        const float wt = wp[t];
        acc[0] = fmaf(wt, __uint_as_float(hv.x << 16),         acc[0]);
        acc[1] = fmaf(wt, __uint_as_float(hv.x & 0xFFFF0000u), acc[1]);
        acc[2] = fmaf(wt, __uint_as_float(hv.y << 16),         acc[2]);
        acc[3] = fmaf(wt, __uint_as_float(hv.y & 0xFFFF0000u), acc[3]);
      }
#pragma unroll
      for (int j = 0; j < 4; ++j) {
        float v = acc[j];
        s_hf[mg * FSTR_ + cg * 4 + j] = v;
        __hip_bfloat16 hi = __float2bfloat16(v);
        sh_h[0][mg * HSTR_ + cg * 4 + j] = hi;
        sh_l[0][mg * HSTR_ + cg * 4 + j] = __float2bfloat16(v - __bfloat162float(hi));
      }
    }
    __syncthreads();

    // P3: decoder GRU: gh = ctx @ dWhh^T (MFMA, split); gi = prev*dWih + b
    {
      bf16x8 ah2[8], al2[8];
#pragma unroll
      for (int kk = 0; kk < 8; ++kk) {
        ah2[kk] = *(const bf16x8*)&sh_h[0][l16 * HSTR_ + kk * 32 + quad * 8];
        al2[kk] = *(const bf16x8*)&sh_l[0][l16 * HSTR_ + kk * 32 + quad * 8];
      }
      const int g = 16 * wid + l16;
      const __hip_bfloat16* pr = dWhhB + (size_t)g * H_ + quad * 8;
      const __hip_bfloat16* pz = dWhhB + (size_t)(H_ + g) * H_ + quad * 8;
      const __hip_bfloat16* pn = dWhhB + (size_t)(2 * H_ + g) * H_ + quad * 8;
      f32x4 ar = {0.f, 0.f, 0.f, 0.f}, az = ar, anh = ar;
#pragma unroll
      for (int kk = 0; kk < 8; ++kk) {
        bf16x8 br = *(const bf16x8*)(pr + kk * 32);
        bf16x8 bz = *(const bf16x8*)(pz + kk * 32);
        bf16x8 bn = *(const bf16x8*)(pn + kk * 32);
        ar  = mfma16(al2[kk], br, ar);  ar  = mfma16(ah2[kk], br, ar);
        az  = mfma16(al2[kk], bz, az);  az  = mfma16(ah2[kk], bz, az);
        anh = mfma16(al2[kk], bn, anh); anh = mfma16(ah2[kk], bn, anh);
      }
      const float dr = s_dbr[g], dz = s_dbz[g], din = s_dbin[g], dhn = s_dbhn[g];
      const float wir = s_dwih[g], wiz = s_dwih[H_ + g], win = s_dwih[2 * H_ + g];
#pragma unroll
      for (int i = 0; i < 4; ++i) {
        const int m = quad * 4 + i;
        const float pv = s_prev[m];
        float r = sigm_(ar[i] + pv * wir + dr);
        float z = sigm_(az[i] + pv * wiz + dz);
        float n = tanh_(pv * win + din + r * (anh[i] + dhn));
        float ctxv = s_hf[m * FSTR_ + g];
        float hd = (1.0f - z) * n + z * ctxv;
        __hip_bfloat16 hi = __float2bfloat16(hd);
        sh_h[1][m * HSTR_ + g] = hi;
        sh_l[1][m * HSTR_ + g] = __float2bfloat16(hd - __bfloat162float(hi));
      }
    }
    __syncthreads();

    // P4: fc1 + relu (MFMA, split) -> fp32 in s_scr
    {
      bf16x8 ad[8], adl[8];
#pragma unroll
      for (int kk = 0; kk < 8; ++kk) {
        ad[kk]  = *(const bf16x8*)&sh_h[1][l16 * HSTR_ + kk * 32 + quad * 8];
        adl[kk] = *(const bf16x8*)&sh_l[1][l16 * HSTR_ + kk * 32 + quad * 8];
      }
      const int j = 16 * wid + l16;
      const __hip_bfloat16* pw = f1WB + (size_t)j * H_ + quad * 8;
      f32x4 a1 = {0.f, 0.f, 0.f, 0.f};
#pragma unroll
      for (int kk = 0; kk < 8; ++kk) {
        bf16x8 bw = *(const bf16x8*)(pw + kk * 32);
        a1 = mfma16(adl[kk], bw, a1);
        a1 = mfma16(ad[kk],  bw, a1);
      }
      const float bj = s_f1b[j];
#pragma unroll
      for (int i = 0; i < 4; ++i) {
        const int m = quad * 4 + i;
        s_scr[m * SSTR_ + j] = fmaxf(a1[i] + bj, 0.0f);
      }
    }
    __syncthreads();

    // P5: fc2 (fp32 dot) -> out, update prev
    {
      const float* ap = &s_scr[mg * SSTR_ + cg * 4];
      float p = 0.f;
#pragma unroll
      for (int j = 0; j < 4; ++j)
        p += ap[j] * s_f2w[cg * 4 + j];
#pragma unroll
      for (int off = 32; off >= 1; off >>= 1) p += __shfl_xor(p, off, 64);
      if (cg == 0) {
        float o = p + s_f2b;
        s_prev[mg] = o;
        dout[(size_t)(b0 + mg) * OUT_ + s] = o;
      }
    }
    __syncthreads();
  }
}

extern "C" void kernel_launch(void* const* d_in, const int* in_sizes, int n_in,
                              void* d_out, int out_size, void* d_ws, size_t ws_size,
                              hipStream_t stream) {
  (void)in_sizes; (void)n_in; (void)out_size; (void)ws_size;
  const float* x    = (const float*)d_in[0];
  const float* h0   = (const float*)d_in[1];
  const float* eWih = (const float*)d_in[2];
  const float* eWhh = (const float*)d_in[3];
  const float* ebih = (const float*)d_in[4];
  const float* ebhh = (const float*)d_in[5];
  const float* dWih = (const float*)d_in[6];
  const float* dWhh = (const float*)d_in[7];
  const float* dbih = (const float*)d_in[8];
  const float* dbhh = (const float*)d_in[9];
  const float* aWq  = (const float*)d_in[10];
  const float* abq  = (const float*)d_in[11];
  const float* f1W  = (const float*)d_in[12];
  const float* f1b  = (const float*)d_in[13];
  const float* f2W  = (const float*)d_in[14];
  const float* f2b  = (const float*)d_in[15];

  __hip_bfloat16* hs = (__hip_bfloat16*)d_ws;   // 134,217,728 B
  __hip_bfloat16* wb = (__hip_bfloat16*)((char*)d_ws + (size_t)B_ * T_ * H_ * 2);

  hipLaunchKernelGGL(af_convert_weights, dim3(256), dim3(256), 0, stream,
                     eWih, eWhh, dWhh, f1W, wb);
  hipLaunchKernelGGL(af_fused_kernel, dim3(NB_), dim3(NTH_), 0, stream,
                     x, h0, ebih, ebhh, dWih, dbih, dbhh, aWq, abq, f1b, f2W, f2b,
                     wb + W_EIH_, wb + W_EHH_, wb + W_DHH_, wb + W_F1_,
                     hs, (float*)d_out);
}

// Round 3
// 2467.153 us; speedup vs baseline: 3.4459x; 1.2903x over previous
//
#include <hip/hip_runtime.h>
#include <hip/hip_bf16.h>

// AttentiveFuturecaster: fused GRU-encoder + attentive GRU-decoder + FC head.
// Round 5: R2 topology (BT=16, NTH=512, grid=128 — best known: 2792us) +
// register-ring software pipelining of the weight streams. Diagnosis: encoder
// is bound by outstanding-load concurrency on the per-step weight stream
// (480 x 1KB loads/CU/step, ~300-450cy latency, only ~4 in flight at the old
// VGPR=64/128 binaries). LDS (125KB) caps at 1 block/CU = 8 waves regardless
// of VGPR<=256, so VGPR 256 is free: launch_bounds(512,2) + explicit depth-6
// gate-triple ring (18 loads in flight/wave). Weights are t-invariant, so the
// next step's first 6 triples are re-issued during the output phase (cross-
// barrier prefetch). Decoder: P3 ring prefetched at P2 start, P4 ring, P2
// double-buffered 4xuint4 hs stream. Accumulation order preserved exactly ->
// absmax must remain 0.0004882812.
// ws layout: [0, 128MB): hs bf16 [B,T,H]; then 1MB bf16 weight blob.

#define B_    2048
#define T_    128
#define F_    64
#define H_    256
#define OUT_  32
#define BT_   16
#define NTH_  512
#define NB_   (B_ / BT_)
#define PD_   6     // weight-ring pipeline depth (gate-triples)
#define HSTR_ 264   // bf16 h-tile LDS row stride
#define FSTR_ 260   // fp32 h-tile LDS row stride
#define XSTR_ 72    // bf16 x-tile LDS row stride
#define SSTR_ 260   // fp32 scratch row stride (softmax w / fc1 out)

// bf16 weight blob element offsets inside ws (after hs)
#define W_EIH_  0
#define W_EHH_  (W_EIH_ + 3 * H_ * F_)     // 49152
#define W_DHH_  (W_EHH_ + 3 * H_ * H_)     // 245760
#define W_F1_   (W_DHH_ + 3 * H_ * H_)     // 442368
#define W_TOT_  (W_F1_ + H_ * H_)          // 507904

typedef __attribute__((ext_vector_type(8))) short bf16x8;
typedef __attribute__((ext_vector_type(4))) float f32x4;

__device__ __forceinline__ f32x4 mfma16(bf16x8 a, bf16x8 b, f32x4 c) {
  return __builtin_amdgcn_mfma_f32_16x16x32_bf16(a, b, c, 0, 0, 0);
}
__device__ __forceinline__ float sigm_(float x) { return 1.0f / (1.0f + __expf(-x)); }
__device__ __forceinline__ float tanh_(float x) {
  x = fminf(15.0f, fmaxf(-15.0f, x));
  float e = __expf(2.0f * x);
  return (e - 1.0f) / (e + 1.0f);
}

__global__ __launch_bounds__(256) void af_convert_weights(
    const float* __restrict__ eWih, const float* __restrict__ eWhh,
    const float* __restrict__ dWhh, const float* __restrict__ f1W,
    __hip_bfloat16* __restrict__ wb) {
  for (int i = blockIdx.x * blockDim.x + threadIdx.x; i < W_TOT_;
       i += gridDim.x * blockDim.x) {
    float v;
    if (i < W_EHH_)      v = eWih[i - W_EIH_];
    else if (i < W_DHH_) v = eWhh[i - W_EHH_];
    else if (i < W_F1_)  v = dWhh[i - W_DHH_];
    else                 v = f1W[i - W_F1_];
    wb[i] = __float2bfloat16(v);
  }
}

__global__ __launch_bounds__(NTH_, 2) void af_fused_kernel(
    const float* __restrict__ x,
    const float* __restrict__ h0,
    const float* __restrict__ ebih,
    const float* __restrict__ ebhh,
    const float* __restrict__ dWih,
    const float* __restrict__ dbih,
    const float* __restrict__ dbhh,
    const float* __restrict__ aWq,
    const float* __restrict__ abq,
    const float* __restrict__ f1b,
    const float* __restrict__ f2W,
    const float* __restrict__ f2b,
    const __hip_bfloat16* __restrict__ eWihB,
    const __hip_bfloat16* __restrict__ eWhhB,
    const __hip_bfloat16* __restrict__ dWhhB,
    const __hip_bfloat16* __restrict__ f1WB,
    __hip_bfloat16* __restrict__ hs,     // [B,T,H] bf16 (workspace)
    float* __restrict__ dout)            // [B,OUT] fp32
{
  __shared__ __hip_bfloat16 sh_h[2][BT_ * HSTR_];   // h hi (bf16)
  __shared__ __hip_bfloat16 sh_l[2][BT_ * HSTR_];   // h lo (bf16 residual)
  __shared__ float          s_hf[2][BT_ * FSTR_];   // h fp32 (carried state)
  __shared__ __hip_bfloat16 sh_x[2][BT_ * XSTR_];   // x hi
  __shared__ __hip_bfloat16 sh_xl[2][BT_ * XSTR_];  // x lo
  __shared__ float s_A[BT_ * T_], s_C[BT_ * T_];    // rank-1 attention tables
  __shared__ float s_ebr[H_], s_ebz[H_], s_ebin[H_], s_ebhn[H_];
  __shared__ float s_dbr[H_], s_dbz[H_], s_dbin[H_], s_dbhn[H_];
  __shared__ float s_dwih[3 * H_];
  __shared__ float s_wq[H_], s_bq[H_], s_f1b[H_], s_f2w[H_];
  __shared__ float s_f2b;
  __shared__ float s_prev[BT_];
  __shared__ float s_scr[BT_ * SSTR_];  // softmax w (cols 0..127) / fc1 out (cols 0..255)

  const int tid  = threadIdx.x;
  const int b0   = blockIdx.x * BT_;
  const int lane = tid & 63;
  const int wid  = tid >> 6;     // 0..7
  const int quad = lane >> 4;    // 0..3
  const int l16  = lane & 15;    // 0..15
  const int mg   = tid >> 5;     // 0..15: batch row for 32-thread-group phases
  const int cg   = tid & 31;     // 0..31: position within group

  // A-operand fragments (shared across phases) + weight register ring
  bf16x8 ah[8], al[8], ax[2], axl[2];
  bf16x8 rb[PD_], rz[PD_], rn[PD_];

  // ---- pipelined weight loaders (addresses are step-invariant) ----
  auto load_enc = [&](int j) {            // j in [0,20)
    const int slot = j % PD_;
    const int s2 = j < 10 ? 0 : 1;
    const int lo = j - s2 * 10;
    const int g = 16 * (2 * wid + s2) + l16;
    if (lo < 8) {
      const __hip_bfloat16* p = eWhhB + (size_t)g * H_ + lo * 32 + quad * 8;
      rb[slot] = *(const bf16x8*)p;
      rz[slot] = *(const bf16x8*)(p + H_ * H_);
      rn[slot] = *(const bf16x8*)(p + 2 * H_ * H_);
    } else {
      const __hip_bfloat16* p = eWihB + (size_t)g * F_ + (lo - 8) * 32 + quad * 8;
      rb[slot] = *(const bf16x8*)p;
      rz[slot] = *(const bf16x8*)(p + H_ * F_);
      rn[slot] = *(const bf16x8*)(p + 2 * H_ * F_);
    }
  };
  auto load_dec = [&](int j) {            // j in [0,16)
    const int slot = j % PD_;
    const int g = 16 * (2 * wid + (j >> 3)) + l16;
    const __hip_bfloat16* p = dWhhB + (size_t)g * H_ + (j & 7) * 32 + quad * 8;
    rb[slot] = *(const bf16x8*)p;
    rz[slot] = *(const bf16x8*)(p + H_ * H_);
    rn[slot] = *(const bf16x8*)(p + 2 * H_ * H_);
  };
  auto load_fc = [&](int j) {             // j in [0,16)
    const int slot = j % PD_;
    const int col = 16 * (2 * wid + (j >> 3)) + l16;
    rb[slot] = *(const bf16x8*)(f1WB + (size_t)col * H_ + (j & 7) * 32 + quad * 8);
  };
  // ---- consumers (lo-split MFMA, order identical to round-2) ----
  auto use_whh = [&](int kk, int slot, f32x4& ar, f32x4& az, f32x4& anh) {
    ar  = mfma16(al[kk], rb[slot], ar);  ar  = mfma16(ah[kk], rb[slot], ar);
    az  = mfma16(al[kk], rz[slot], az);  az  = mfma16(ah[kk], rz[slot], az);
    anh = mfma16(al[kk], rn[slot], anh); anh = mfma16(ah[kk], rn[slot], anh);
  };
  auto use_wih = [&](int kk, int slot, f32x4& ar, f32x4& az, f32x4& ani) {
    ar  = mfma16(axl[kk], rb[slot], ar);  ar  = mfma16(ax[kk], rb[slot], ar);
    az  = mfma16(axl[kk], rz[slot], az);  az  = mfma16(ax[kk], rz[slot], az);
    ani = mfma16(axl[kk], rn[slot], ani); ani = mfma16(ax[kk], rn[slot], ani);
  };
  auto use_fc = [&](int kk, int slot, f32x4& a1) {
    a1 = mfma16(al[kk], rb[slot], a1);
    a1 = mfma16(ah[kk], rb[slot], a1);
  };

  // ---------------- prologue: constants + h0 + x(t=0) into LDS ----------------
  for (int g = tid; g < H_; g += NTH_) {
    s_ebr[g]  = ebih[g]          + ebhh[g];
    s_ebz[g]  = ebih[H_ + g]     + ebhh[H_ + g];
    s_ebin[g] = ebih[2 * H_ + g];
    s_ebhn[g] = ebhh[2 * H_ + g];
    s_dbr[g]  = dbih[g]          + dbhh[g];
    s_dbz[g]  = dbih[H_ + g]     + dbhh[H_ + g];
    s_dbin[g] = dbih[2 * H_ + g];
    s_dbhn[g] = dbhh[2 * H_ + g];
    s_wq[g]   = aWq[g];
    s_bq[g]   = abq[g];
    s_f1b[g]  = f1b[g];
    s_f2w[g]  = f2W[g];
  }
  for (int g = tid; g < 3 * H_; g += NTH_) s_dwih[g] = dWih[g];
  if (tid == 0) s_f2b = f2b[0];

  {
    const float* hp = h0 + (size_t)(b0 + mg) * H_ + cg * 8;
    float4 v0 = *(const float4*)(hp);
    float4 v1 = *(const float4*)(hp + 4);
    float vv[8] = {v0.x, v0.y, v0.z, v0.w, v1.x, v1.y, v1.z, v1.w};
#pragma unroll
    for (int j = 0; j < 8; ++j) {
      float v = vv[j];
      s_hf[0][mg * FSTR_ + cg * 8 + j] = v;
      __hip_bfloat16 hi = __float2bfloat16(v);
      sh_h[0][mg * HSTR_ + cg * 8 + j] = hi;
      sh_l[0][mg * HSTR_ + cg * 8 + j] = __float2bfloat16(v - __bfloat162float(hi));
    }
    float2 xv = *(const float2*)(x + ((size_t)(b0 + mg) * T_) * F_ + cg * 2);
    __hip_bfloat16 xh0 = __float2bfloat16(xv.x);
    __hip_bfloat16 xh1 = __float2bfloat16(xv.y);
    sh_x[0][mg * XSTR_ + cg * 2]      = xh0;
    sh_x[0][mg * XSTR_ + cg * 2 + 1]  = xh1;
    sh_xl[0][mg * XSTR_ + cg * 2]     = __float2bfloat16(xv.x - __bfloat162float(xh0));
    sh_xl[0][mg * XSTR_ + cg * 2 + 1] = __float2bfloat16(xv.y - __bfloat162float(xh1));
  }
  // initial weight-ring prefetch (overlaps the prologue barrier)
#pragma unroll
  for (int j = 0; j < PD_; ++j) load_enc(j);
  __syncthreads();

  // ============================ ENCODER: 128 GRU steps ============================
  int cur = 0;
  for (int t = 0; t < T_; ++t) {
    const int nxt = cur ^ 1;
#pragma unroll
    for (int kk = 0; kk < 8; ++kk) {
      ah[kk] = *(const bf16x8*)&sh_h[cur][l16 * HSTR_ + kk * 32 + quad * 8];
      al[kk] = *(const bf16x8*)&sh_l[cur][l16 * HSTR_ + kk * 32 + quad * 8];
    }
#pragma unroll
    for (int kk = 0; kk < 2; ++kk) {
      ax[kk]  = *(const bf16x8*)&sh_x[cur][l16 * XSTR_ + kk * 32 + quad * 8];
      axl[kk] = *(const bf16x8*)&sh_xl[cur][l16 * XSTR_ + kk * 32 + quad * 8];
    }

    f32x4 z4 = {0.f, 0.f, 0.f, 0.f};
    f32x4 ar0 = z4, az0 = z4, ani0 = z4, anh0 = z4;
    f32x4 ar1 = z4, az1 = z4, ani1 = z4, anh1 = z4;

#pragma unroll
    for (int j = 0; j < 20; ++j) {
      if (j < 8)       use_whh(j,      j % PD_, ar0, az0, anh0);
      else if (j < 10) use_wih(j - 8,  j % PD_, ar0, az0, ani0);
      else if (j < 18) use_whh(j - 10, j % PD_, ar1, az1, anh1);
      else             use_wih(j - 18, j % PD_, ar1, az1, ani1);
      if (j + PD_ < 20) load_enc(j + PD_);

      if (j == 9 || j == 19) {
        const int s2 = (j == 9) ? 0 : 1;
        const f32x4& ar = (j == 9) ? ar0 : ar1;
        const f32x4& az = (j == 9) ? az0 : az1;
        const f32x4& ani = (j == 9) ? ani0 : ani1;
        const f32x4& anh = (j == 9) ? anh0 : anh1;
        const int g = 16 * (2 * wid + s2) + l16;
        const float br_ = s_ebr[g], bz_ = s_ebz[g], bin_ = s_ebin[g], bhn_ = s_ebhn[g];
#pragma unroll
        for (int i = 0; i < 4; ++i) {
          const int m = quad * 4 + i;     // D row = batch
          float r = sigm_(ar[i] + br_);
          float z = sigm_(az[i] + bz_);
          float n = tanh_(ani[i] + bin_ + r * (anh[i] + bhn_));
          float hold = s_hf[cur][m * FSTR_ + g];
          float hn = (1.0f - z) * n + z * hold;
          s_hf[nxt][m * FSTR_ + g] = hn;
          __hip_bfloat16 hi = __float2bfloat16(hn);
          sh_h[nxt][m * HSTR_ + g] = hi;
          sh_l[nxt][m * HSTR_ + g] = __float2bfloat16(hn - __bfloat162float(hi));
        }
      }
    }
    __syncthreads();

    // output phase: next-step weight prefetch, hs store, A/C dots, x prefetch
    if (t + 1 < T_) {
#pragma unroll
      for (int j = 0; j < PD_; ++j) load_enc(j);   // cross-barrier ring refill
    }
    {
      uint4 hv = *(const uint4*)&sh_h[nxt][mg * HSTR_ + cg * 8];
      *(uint4*)&hs[((size_t)(b0 + mg) * T_ + t) * H_ + cg * 8] = hv;
      const float* hp = &s_hf[nxt][mg * FSTR_ + cg * 8];
      float pa = 0.f, pc = 0.f;
#pragma unroll
      for (int j = 0; j < 8; ++j) {
        float hvf = hp[j];
        pa += hvf * s_wq[cg * 8 + j];
        pc += hvf * s_bq[cg * 8 + j];
      }
#pragma unroll
      for (int off = 16; off >= 1; off >>= 1) {
        pa += __shfl_xor(pa, off, 64);
        pc += __shfl_xor(pc, off, 64);
      }
      if (cg == 0) {
        s_A[mg * T_ + t] = pa;
        s_C[mg * T_ + t] = pc;
      }
      if (t + 1 < T_) {
        float2 xv = *(const float2*)(x + ((size_t)(b0 + mg) * T_ + (t + 1)) * F_ + cg * 2);
        __hip_bfloat16 xh0 = __float2bfloat16(xv.x);
        __hip_bfloat16 xh1 = __float2bfloat16(xv.y);
        sh_x[nxt][mg * XSTR_ + cg * 2]      = xh0;
        sh_x[nxt][mg * XSTR_ + cg * 2 + 1]  = xh1;
        sh_xl[nxt][mg * XSTR_ + cg * 2]     = __float2bfloat16(xv.x - __bfloat162float(xh0));
        sh_xl[nxt][mg * XSTR_ + cg * 2 + 1] = __float2bfloat16(xv.y - __bfloat162float(xh1));
      }
    }
    __syncthreads();
    cur = nxt;
  }

  // ============================ DECODER: 32 steps ============================
  if (tid < BT_)
    s_prev[tid] = x[((size_t)(b0 + tid) * T_ + (T_ - 1)) * F_];
  __syncthreads();

  for (int s = 0; s < OUT_; ++s) {
    // P1: scores = (prev*A + C)*scale, softmax over T per batch row -> s_scr
    {
      float4 a4 = *(const float4*)(s_A + mg * T_ + cg * 4);
      float4 c4 = *(const float4*)(s_C + mg * T_ + cg * 4);
      const float pv = s_prev[mg];
      float sc0 = (pv * a4.x + c4.x) * 0.0625f;
      float sc1 = (pv * a4.y + c4.y) * 0.0625f;
      float sc2 = (pv * a4.z + c4.z) * 0.0625f;
      float sc3 = (pv * a4.w + c4.w) * 0.0625f;
      float mx = fmaxf(fmaxf(sc0, sc1), fmaxf(sc2, sc3));
#pragma unroll
      for (int off = 16; off >= 1; off >>= 1) mx = fmaxf(mx, __shfl_xor(mx, off, 64));
      float e0 = __expf(sc0 - mx), e1 = __expf(sc1 - mx);
      float e2 = __expf(sc2 - mx), e3 = __expf(sc3 - mx);
      float ss = e0 + e1 + e2 + e3;
#pragma unroll
      for (int off = 16; off >= 1; off >>= 1) ss += __shfl_xor(ss, off, 64);
      const float inv = 1.0f / ss;
      float4 wv = make_float4(e0 * inv, e1 * inv, e2 * inv, e3 * inv);
      *(float4*)&s_scr[mg * SSTR_ + cg * 4] = wv;
    }
    __syncthreads();

    // P2: ctx[m,h] = sum_t w[m,t] * hs[m,t,h]  (fp32 VALU, bf16 loads,
    //     double-buffered 4x uint4) + P3 weight-ring prefetch up front
    {
#pragma unroll
      for (int j = 0; j < PD_; ++j) load_dec(j);

      float acc[8] = {0.f, 0.f, 0.f, 0.f, 0.f, 0.f, 0.f, 0.f};
      const __hip_bfloat16* hp = hs + (size_t)(b0 + mg) * T_ * H_ + cg * 8;
      const float* wp = &s_scr[mg * SSTR_];
      uint4 bA[4], bB[4];
#pragma unroll
      for (int u = 0; u < 4; ++u) bA[u] = *(const uint4*)(hp + (size_t)u * H_);
      auto p2fma = [&](const uint4& hv, float wt) {
        acc[0] = fmaf(wt, __uint_as_float(hv.x << 16),         acc[0]);
        acc[1] = fmaf(wt, __uint_as_float(hv.x & 0xFFFF0000u), acc[1]);
        acc[2] = fmaf(wt, __uint_as_float(hv.y << 16),         acc[2]);
        acc[3] = fmaf(wt, __uint_as_float(hv.y & 0xFFFF0000u), acc[3]);
        acc[4] = fmaf(wt, __uint_as_float(hv.z << 16),         acc[4]);
        acc[5] = fmaf(wt, __uint_as_float(hv.z & 0xFFFF0000u), acc[5]);
        acc[6] = fmaf(wt, __uint_as_float(hv.w << 16),         acc[6]);
        acc[7] = fmaf(wt, __uint_as_float(hv.w & 0xFFFF0000u), acc[7]);
      };
      for (int tb = 0; tb < T_; tb += 8) {
#pragma unroll
        for (int u = 0; u < 4; ++u) bB[u] = *(const uint4*)(hp + (size_t)(tb + 4 + u) * H_);
#pragma unroll
        for (int u = 0; u < 4; ++u) p2fma(bA[u], wp[tb + u]);
        if (tb + 8 < T_) {
#pragma unroll
          for (int u = 0; u < 4; ++u) bA[u] = *(const uint4*)(hp + (size_t)(tb + 8 + u) * H_);
        }
#pragma unroll
        for (int u = 0; u < 4; ++u) p2fma(bB[u], wp[tb + 4 + u]);
      }
#pragma unroll
      for (int j = 0; j < 8; ++j) {
        float v = acc[j];
        s_hf[0][mg * FSTR_ + cg * 8 + j] = v;
        __hip_bfloat16 hi = __float2bfloat16(v);
        sh_h[0][mg * HSTR_ + cg * 8 + j] = hi;
        sh_l[0][mg * HSTR_ + cg * 8 + j] = __float2bfloat16(v - __bfloat162float(hi));
      }
    }
    __syncthreads();

    // P3: decoder GRU: gh = ctx @ dWhh^T (MFMA ring); gi = prev*dWih + b
    {
#pragma unroll
      for (int kk = 0; kk < 8; ++kk) {
        ah[kk] = *(const bf16x8*)&sh_h[0][l16 * HSTR_ + kk * 32 + quad * 8];
        al[kk] = *(const bf16x8*)&sh_l[0][l16 * HSTR_ + kk * 32 + quad * 8];
      }
      f32x4 z4 = {0.f, 0.f, 0.f, 0.f};
      f32x4 ar0 = z4, az0 = z4, anh0 = z4;
      f32x4 ar1 = z4, az1 = z4, anh1 = z4;
#pragma unroll
      for (int j = 0; j < 16; ++j) {
        if (j < 8) use_whh(j,     j % PD_, ar0, az0, anh0);
        else       use_whh(j - 8, j % PD_, ar1, az1, anh1);
        if (j + PD_ < 16) load_dec(j + PD_);

        if (j == 7 || j == 15) {
          const int s2 = (j == 7) ? 0 : 1;
          const f32x4& ar = (j == 7) ? ar0 : ar1;
          const f32x4& az = (j == 7) ? az0 : az1;
          const f32x4& anh = (j == 7) ? anh0 : anh1;
          const int g = 16 * (2 * wid + s2) + l16;
          const float dr = s_dbr[g], dz = s_dbz[g], din = s_dbin[g], dhn = s_dbhn[g];
          const float wir = s_dwih[g], wiz = s_dwih[H_ + g], win = s_dwih[2 * H_ + g];
#pragma unroll
          for (int i = 0; i < 4; ++i) {
            const int m = quad * 4 + i;
            const float pv = s_prev[m];
            float r = sigm_(ar[i] + pv * wir + dr);
            float z = sigm_(az[i] + pv * wiz + dz);
            float n = tanh_(pv * win + din + r * (anh[i] + dhn));
            float ctxv = s_hf[0][m * FSTR_ + g];
            float hd = (1.0f - z) * n + z * ctxv;
            __hip_bfloat16 hi = __float2bfloat16(hd);
            sh_h[1][m * HSTR_ + g] = hi;
            sh_l[1][m * HSTR_ + g] = __float2bfloat16(hd - __bfloat162float(hi));
          }
        }
      }
    }
    __syncthreads();

    // P4: fc1 + relu (MFMA ring) -> fp32 in s_scr
    {
#pragma unroll
      for (int kk = 0; kk < 8; ++kk) {
        ah[kk] = *(const bf16x8*)&sh_h[1][l16 * HSTR_ + kk * 32 + quad * 8];  // ad
        al[kk] = *(const bf16x8*)&sh_l[1][l16 * HSTR_ + kk * 32 + quad * 8];  // adl
      }
#pragma unroll
      for (int j = 0; j < PD_; ++j) load_fc(j);
      f32x4 z4 = {0.f, 0.f, 0.f, 0.f};
      f32x4 a10 = z4, a11 = z4;
#pragma unroll
      for (int j = 0; j < 16; ++j) {
        if (j < 8) use_fc(j,     j % PD_, a10);
        else       use_fc(j - 8, j % PD_, a11);
        if (j + PD_ < 16) load_fc(j + PD_);

        if (j == 7 || j == 15) {
          const int s2 = (j == 7) ? 0 : 1;
          const f32x4& a1 = (j == 7) ? a10 : a11;
          const int jcol = 16 * (2 * wid + s2) + l16;
          const float bj = s_f1b[jcol];
#pragma unroll
          for (int i = 0; i < 4; ++i) {
            const int m = quad * 4 + i;
            s_scr[m * SSTR_ + jcol] = fmaxf(a1[i] + bj, 0.0f);
          }
        }
      }
    }
    __syncthreads();

    // P5: fc2 (fp32 dot) -> out, update prev
    {
      const float* ap = &s_scr[mg * SSTR_ + cg * 8];
      float p = 0.f;
#pragma unroll
      for (int j = 0; j < 8; ++j)
        p += ap[j] * s_f2w[cg * 8 + j];
#pragma unroll
      for (int off = 16; off >= 1; off >>= 1) p += __shfl_xor(p, off, 64);
      if (cg == 0) {
        float o = p + s_f2b;
        s_prev[mg] = o;
        dout[(size_t)(b0 + mg) * OUT_ + s] = o;
      }
    }
    __syncthreads();
  }
}

extern "C" void kernel_launch(void* const* d_in, const int* in_sizes, int n_in,
                              void* d_out, int out_size, void* d_ws, size_t ws_size,
                              hipStream_t stream) {
  (void)in_sizes; (void)n_in; (void)out_size; (void)ws_size;
  const float* x    = (const float*)d_in[0];
  const float* h0   = (const float*)d_in[1];
  const float* eWih = (const float*)d_in[2];
  const float* eWhh = (const float*)d_in[3];
  const float* ebih = (const float*)d_in[4];
  const float* ebhh = (const float*)d_in[5];
  const float* dWih = (const float*)d_in[6];
  const float* dWhh = (const float*)d_in[7];
  const float* dbih = (const float*)d_in[8];
  const float* dbhh = (const float*)d_in[9];
  const float* aWq  = (const float*)d_in[10];
  const float* abq  = (const float*)d_in[11];
  const float* f1W  = (const float*)d_in[12];
  const float* f1b  = (const float*)d_in[13];
  const float* f2W  = (const float*)d_in[14];
  const float* f2b  = (const float*)d_in[15];

  __hip_bfloat16* hs = (__hip_bfloat16*)d_ws;   // 134,217,728 B
  __hip_bfloat16* wb = (__hip_bfloat16*)((char*)d_ws + (size_t)B_ * T_ * H_ * 2);

  hipLaunchKernelGGL(af_convert_weights, dim3(256), dim3(256), 0, stream,
                     eWih, eWhh, dWhh, f1W, wb);
  hipLaunchKernelGGL(af_fused_kernel, dim3(NB_), dim3(NTH_), 0, stream,
                     x, h0, ebih, ebhh, dWih, dbih, dbhh, aWq, abq, f1b, f2W, f2b,
                     wb + W_EIH_, wb + W_EHH_, wb + W_DHH_, wb + W_F1_,
                     hs, (float*)d_out);
}

// Round 4
// 1941.755 us; speedup vs baseline: 4.3783x; 1.2706x over previous
//
#include <hip/hip_runtime.h>
#include <hip/hip_bf16.h>

// AttentiveFuturecaster: fused GRU-encoder + attentive GRU-decoder + FC head.
// Round 6 (on R5's 2467us): three structural changes, numerics bit-identical.
// 1) PACKED WEIGHTS: convert kernel permutes weights into MFMA-fragment order
//    (1KB contiguous per wave-load instead of 16 scattered 64B rows). Loaders
//    become base + chunk*512 + lane*8.
// 2) SINGLE-BARRIER ENCODER STEP: with [cur]/[nxt] double-buffering, the
//    hs-store / A-C dots / x-prefetch (shifted to index t-1) merge into the
//    MFMA phase; 2 barriers/step -> 1 (256 -> 128 drains + phase overlap).
// 3) DECODER 5 -> 3 barriers: P1->P2 and P5->P1 dataflow is same-32-lane-
//    group (wave-internal LDS is program-ordered); prev carried in registers
//    for P1. P2 hs stream deepened to 8+8 uint4 in flight.
// ws layout: [0, 128MB): hs bf16 [B,T,H]; then 1MB PACKED bf16 weight blob.

#define B_    2048
#define T_    128
#define F_    64
#define H_    256
#define OUT_  32
#define BT_   16
#define NTH_  512
#define NB_   (B_ / BT_)
#define PD_   6     // weight-ring pipeline depth (gate-triples)
#define HSTR_ 264   // bf16 h-tile LDS row stride
#define FSTR_ 260   // fp32 h-tile LDS row stride
#define XSTR_ 72    // bf16 x-tile LDS row stride
#define SSTR_ 260   // fp32 scratch row stride (softmax w / fc1 out)

// PACKED bf16 weight blob element offsets inside ws (after hs).
// Layout: chunks of 512 elements (1KB). eWhh/dWhh: chunk=((c*8+kk)*3+q),
// eWih: ((c*2+kk)*3+q), f1W: (c*8+kk). Within chunk: lane*8+e, where the
// fragment for lane (quad=lane>>4,l16=lane&15) is row q*H+16c+l16,
// cols kk*32+quad*8+e  — exactly the old per-lane load addresses.
#define PK_EHH_ 0
#define PK_EIH_ (PK_EHH_ + 3 * H_ * H_)    // 196608
#define PK_DHH_ (PK_EIH_ + 3 * H_ * F_)    // 245760
#define PK_F1_  (PK_DHH_ + 3 * H_ * H_)    // 442368
#define W_TOT_  (PK_F1_ + H_ * H_)         // 507904

typedef __attribute__((ext_vector_type(8))) short bf16x8;
typedef __attribute__((ext_vector_type(4))) float f32x4;

__device__ __forceinline__ f32x4 mfma16(bf16x8 a, bf16x8 b, f32x4 c) {
  return __builtin_amdgcn_mfma_f32_16x16x32_bf16(a, b, c, 0, 0, 0);
}
__device__ __forceinline__ float sigm_(float x) { return 1.0f / (1.0f + __expf(-x)); }
__device__ __forceinline__ float tanh_(float x) {
  x = fminf(15.0f, fmaxf(-15.0f, x));
  float e = __expf(2.0f * x);
  return (e - 1.0f) / (e + 1.0f);
}

__global__ __launch_bounds__(256) void af_convert_weights(
    const float* __restrict__ eWih, const float* __restrict__ eWhh,
    const float* __restrict__ dWhh, const float* __restrict__ f1W,
    __hip_bfloat16* __restrict__ wb) {
  for (int i = blockIdx.x * blockDim.x + threadIdx.x; i < W_TOT_;
       i += gridDim.x * blockDim.x) {
    float v;
    int o, chunk, r, ln, e, q, ck, c, kk, row, col;
    if (i < PK_EIH_) {            // packed eWhh
      o = i;
      chunk = o >> 9; r = o & 511; ln = r >> 3; e = r & 7;
      q = chunk % 3; ck = chunk / 3; c = ck >> 3; kk = ck & 7;
      row = q * H_ + c * 16 + (ln & 15);
      col = kk * 32 + (ln >> 4) * 8 + e;
      v = eWhh[row * H_ + col];
    } else if (i < PK_DHH_) {     // packed eWih
      o = i - PK_EIH_;
      chunk = o >> 9; r = o & 511; ln = r >> 3; e = r & 7;
      q = chunk % 3; ck = chunk / 3; c = ck >> 1; kk = ck & 1;
      row = q * H_ + c * 16 + (ln & 15);
      col = kk * 32 + (ln >> 4) * 8 + e;
      v = eWih[row * F_ + col];
    } else if (i < PK_F1_) {      // packed dWhh
      o = i - PK_DHH_;
      chunk = o >> 9; r = o & 511; ln = r >> 3; e = r & 7;
      q = chunk % 3; ck = chunk / 3; c = ck >> 3; kk = ck & 7;
      row = q * H_ + c * 16 + (ln & 15);
      col = kk * 32 + (ln >> 4) * 8 + e;
      v = dWhh[row * H_ + col];
    } else {                      // packed f1W
      o = i - PK_F1_;
      chunk = o >> 9; r = o & 511; ln = r >> 3; e = r & 7;
      c = chunk >> 3; kk = chunk & 7;
      row = c * 16 + (ln & 15);
      col = kk * 32 + (ln >> 4) * 8 + e;
      v = f1W[row * H_ + col];
    }
    wb[i] = __float2bfloat16(v);
  }
}

__global__ __launch_bounds__(NTH_, 2) void af_fused_kernel(
    const float* __restrict__ x,
    const float* __restrict__ h0,
    const float* __restrict__ ebih,
    const float* __restrict__ ebhh,
    const float* __restrict__ dWih,
    const float* __restrict__ dbih,
    const float* __restrict__ dbhh,
    const float* __restrict__ aWq,
    const float* __restrict__ abq,
    const float* __restrict__ f1b,
    const float* __restrict__ f2W,
    const float* __restrict__ f2b,
    const __hip_bfloat16* __restrict__ eWihB,   // packed
    const __hip_bfloat16* __restrict__ eWhhB,   // packed
    const __hip_bfloat16* __restrict__ dWhhB,   // packed
    const __hip_bfloat16* __restrict__ f1WB,    // packed
    __hip_bfloat16* __restrict__ hs,     // [B,T,H] bf16 (workspace)
    float* __restrict__ dout)            // [B,OUT] fp32
{
  __shared__ __hip_bfloat16 sh_h[2][BT_ * HSTR_];   // h hi (bf16)
  __shared__ __hip_bfloat16 sh_l[2][BT_ * HSTR_];   // h lo (bf16 residual)
  __shared__ float          s_hf[2][BT_ * FSTR_];   // h fp32 (carried state)
  __shared__ __hip_bfloat16 sh_x[2][BT_ * XSTR_];   // x hi
  __shared__ __hip_bfloat16 sh_xl[2][BT_ * XSTR_];  // x lo
  __shared__ float s_A[BT_ * T_], s_C[BT_ * T_];    // rank-1 attention tables
  __shared__ float s_ebr[H_], s_ebz[H_], s_ebin[H_], s_ebhn[H_];
  __shared__ float s_dbr[H_], s_dbz[H_], s_dbin[H_], s_dbhn[H_];
  __shared__ float s_dwih[3 * H_];
  __shared__ float s_wq[H_], s_bq[H_], s_f1b[H_], s_f2w[H_];
  __shared__ float s_f2b;
  __shared__ float s_prev[BT_];
  __shared__ float s_scr[BT_ * SSTR_];  // softmax w (cols 0..127) / fc1 out (cols 0..255)

  const int tid  = threadIdx.x;
  const int b0   = blockIdx.x * BT_;
  const int lane = tid & 63;
  const int wid  = tid >> 6;     // 0..7
  const int quad = lane >> 4;    // 0..3
  const int l16  = lane & 15;    // 0..15
  const int mg   = tid >> 5;     // 0..15: batch row for 32-thread-group phases
  const int cg   = tid & 31;     // 0..31: position within group
  const int lofs = lane * 8;     // element offset within a packed 512-elem chunk

  // A-operand fragments (shared across phases) + weight register ring
  bf16x8 ah[8], al[8], ax[2], axl[2];
  bf16x8 rb[PD_], rz[PD_], rn[PD_];

  // ---- pipelined weight loaders: packed chunks, 1KB contiguous per wave ----
  auto load_enc = [&](int j) {            // j in [0,20)
    const int slot = j % PD_;
    const int s2 = j < 10 ? 0 : 1;
    const int lo = j - s2 * 10;
    const int c = 2 * wid + s2;
    const __hip_bfloat16* p;
    if (lo < 8) p = eWhhB + (size_t)((c * 8 + lo) * 3) * 512 + lofs;
    else        p = eWihB + (size_t)((c * 2 + (lo - 8)) * 3) * 512 + lofs;
    rb[slot] = *(const bf16x8*)p;
    rz[slot] = *(const bf16x8*)(p + 512);
    rn[slot] = *(const bf16x8*)(p + 1024);
  };
  auto load_dec = [&](int j) {            // j in [0,16)
    const int slot = j % PD_;
    const __hip_bfloat16* p =
        dWhhB + (size_t)(((2 * wid + (j >> 3)) * 8 + (j & 7)) * 3) * 512 + lofs;
    rb[slot] = *(const bf16x8*)p;
    rz[slot] = *(const bf16x8*)(p + 512);
    rn[slot] = *(const bf16x8*)(p + 1024);
  };
  auto load_fc = [&](int j) {             // j in [0,16)
    const int slot = j % PD_;
    rb[slot] = *(const bf16x8*)(
        f1WB + (size_t)((2 * wid + (j >> 3)) * 8 + (j & 7)) * 512 + lofs);
  };
  // ---- consumers (lo-split MFMA, order identical to round-2) ----
  auto use_whh = [&](int kk, int slot, f32x4& ar, f32x4& az, f32x4& anh) {
    ar  = mfma16(al[kk], rb[slot], ar);  ar  = mfma16(ah[kk], rb[slot], ar);
    az  = mfma16(al[kk], rz[slot], az);  az  = mfma16(ah[kk], rz[slot], az);
    anh = mfma16(al[kk], rn[slot], anh); anh = mfma16(ah[kk], rn[slot], anh);
  };
  auto use_wih = [&](int kk, int slot, f32x4& ar, f32x4& az, f32x4& ani) {
    ar  = mfma16(axl[kk], rb[slot], ar);  ar  = mfma16(ax[kk], rb[slot], ar);
    az  = mfma16(axl[kk], rz[slot], az);  az  = mfma16(ax[kk], rz[slot], az);
    ani = mfma16(axl[kk], rn[slot], ani); ani = mfma16(ax[kk], rn[slot], ani);
  };
  auto use_fc = [&](int kk, int slot, f32x4& a1) {
    a1 = mfma16(al[kk], rb[slot], a1);
    a1 = mfma16(ah[kk], rb[slot], a1);
  };

  // ---------------- prologue: constants + h0 + x(t=0) into LDS ----------------
  for (int g = tid; g < H_; g += NTH_) {
    s_ebr[g]  = ebih[g]          + ebhh[g];
    s_ebz[g]  = ebih[H_ + g]     + ebhh[H_ + g];
    s_ebin[g] = ebih[2 * H_ + g];
    s_ebhn[g] = ebhh[2 * H_ + g];
    s_dbr[g]  = dbih[g]          + dbhh[g];
    s_dbz[g]  = dbih[H_ + g]     + dbhh[H_ + g];
    s_dbin[g] = dbih[2 * H_ + g];
    s_dbhn[g] = dbhh[2 * H_ + g];
    s_wq[g]   = aWq[g];
    s_bq[g]   = abq[g];
    s_f1b[g]  = f1b[g];
    s_f2w[g]  = f2W[g];
  }
  for (int g = tid; g < 3 * H_; g += NTH_) s_dwih[g] = dWih[g];
  if (tid == 0) s_f2b = f2b[0];

  {
    const float* hp = h0 + (size_t)(b0 + mg) * H_ + cg * 8;
    float4 v0 = *(const float4*)(hp);
    float4 v1 = *(const float4*)(hp + 4);
    float vv[8] = {v0.x, v0.y, v0.z, v0.w, v1.x, v1.y, v1.z, v1.w};
#pragma unroll
    for (int j = 0; j < 8; ++j) {
      float v = vv[j];
      s_hf[0][mg * FSTR_ + cg * 8 + j] = v;
      __hip_bfloat16 hi = __float2bfloat16(v);
      sh_h[0][mg * HSTR_ + cg * 8 + j] = hi;
      sh_l[0][mg * HSTR_ + cg * 8 + j] = __float2bfloat16(v - __bfloat162float(hi));
    }
    float2 xv = *(const float2*)(x + ((size_t)(b0 + mg) * T_) * F_ + cg * 2);
    __hip_bfloat16 xh0 = __float2bfloat16(xv.x);
    __hip_bfloat16 xh1 = __float2bfloat16(xv.y);
    sh_x[0][mg * XSTR_ + cg * 2]      = xh0;
    sh_x[0][mg * XSTR_ + cg * 2 + 1]  = xh1;
    sh_xl[0][mg * XSTR_ + cg * 2]     = __float2bfloat16(xv.x - __bfloat162float(xh0));
    sh_xl[0][mg * XSTR_ + cg * 2 + 1] = __float2bfloat16(xv.y - __bfloat162float(xh1));
  }
  // initial weight-ring prefetch (overlaps the prologue barrier)
#pragma unroll
  for (int j = 0; j < PD_; ++j) load_enc(j);
  __syncthreads();

  // ================= ENCODER: 128 GRU steps, ONE barrier per step =================
  // Invariant at step t entry: [cur] holds state S_{t-1} (S_{-1}=h0), sh_x[cur]=x_t.
  // Merged phase: hs[t-1] store + A/C dots (idx t-1) + x_{t+1} prefetch + MFMA step.
  int cur = 0;
  for (int t = 0; t < T_; ++t) {
    const int nxt = cur ^ 1;

    // early global issues: hs store of S_{t-1}; x_{t+1} load
    float2 xv;
    if (t + 1 < T_)
      xv = *(const float2*)(x + ((size_t)(b0 + mg) * T_ + (t + 1)) * F_ + cg * 2);
    if (t > 0) {
      uint4 hv = *(const uint4*)&sh_h[cur][mg * HSTR_ + cg * 8];
      *(uint4*)&hs[((size_t)(b0 + mg) * T_ + (t - 1)) * H_ + cg * 8] = hv;
    }

    // A-fragments from [cur]
#pragma unroll
    for (int kk = 0; kk < 8; ++kk) {
      ah[kk] = *(const bf16x8*)&sh_h[cur][l16 * HSTR_ + kk * 32 + quad * 8];
      al[kk] = *(const bf16x8*)&sh_l[cur][l16 * HSTR_ + kk * 32 + quad * 8];
    }
#pragma unroll
    for (int kk = 0; kk < 2; ++kk) {
      ax[kk]  = *(const bf16x8*)&sh_x[cur][l16 * XSTR_ + kk * 32 + quad * 8];
      axl[kk] = *(const bf16x8*)&sh_xl[cur][l16 * XSTR_ + kk * 32 + quad * 8];
    }

    f32x4 z4 = {0.f, 0.f, 0.f, 0.f};
    f32x4 ar0 = z4, az0 = z4, ani0 = z4, anh0 = z4;
    f32x4 ar1 = z4, az1 = z4, ani1 = z4, anh1 = z4;

#pragma unroll
    for (int j = 0; j < 20; ++j) {
      if (j < 8)       use_whh(j,      j % PD_, ar0, az0, anh0);
      else if (j < 10) use_wih(j - 8,  j % PD_, ar0, az0, ani0);
      else if (j < 18) use_whh(j - 10, j % PD_, ar1, az1, anh1);
      else             use_wih(j - 18, j % PD_, ar1, az1, ani1);
      if (j + PD_ < 20) load_enc(j + PD_);

      if (j == 9 || j == 19) {
        const int s2 = (j == 9) ? 0 : 1;
        const f32x4& ar = (j == 9) ? ar0 : ar1;
        const f32x4& az = (j == 9) ? az0 : az1;
        const f32x4& ani = (j == 9) ? ani0 : ani1;
        const f32x4& anh = (j == 9) ? anh0 : anh1;
        const int g = 16 * (2 * wid + s2) + l16;
        const float br_ = s_ebr[g], bz_ = s_ebz[g], bin_ = s_ebin[g], bhn_ = s_ebhn[g];
#pragma unroll
        for (int i = 0; i < 4; ++i) {
          const int m = quad * 4 + i;     // D row = batch
          float r = sigm_(ar[i] + br_);
          float z = sigm_(az[i] + bz_);
          float n = tanh_(ani[i] + bin_ + r * (anh[i] + bhn_));
          float hold = s_hf[cur][m * FSTR_ + g];
          float hn = (1.0f - z) * n + z * hold;
          s_hf[nxt][m * FSTR_ + g] = hn;
          __hip_bfloat16 hi = __float2bfloat16(hn);
          sh_h[nxt][m * HSTR_ + g] = hi;
          sh_l[nxt][m * HSTR_ + g] = __float2bfloat16(hn - __bfloat162float(hi));
        }
      }
    }

    // A/C dots for index t-1 (from s_hf[cur]); x_{t+1} -> sh_x[nxt]
    if (t > 0) {
      const float* hp = &s_hf[cur][mg * FSTR_ + cg * 8];
      float pa = 0.f, pc = 0.f;
#pragma unroll
      for (int j = 0; j < 8; ++j) {
        float hvf = hp[j];
        pa += hvf * s_wq[cg * 8 + j];
        pc += hvf * s_bq[cg * 8 + j];
      }
#pragma unroll
      for (int off = 16; off >= 1; off >>= 1) {
        pa += __shfl_xor(pa, off, 64);
        pc += __shfl_xor(pc, off, 64);
      }
      if (cg == 0) {
        s_A[mg * T_ + (t - 1)] = pa;
        s_C[mg * T_ + (t - 1)] = pc;
      }
    }
    if (t + 1 < T_) {
      __hip_bfloat16 xh0 = __float2bfloat16(xv.x);
      __hip_bfloat16 xh1 = __float2bfloat16(xv.y);
      sh_x[nxt][mg * XSTR_ + cg * 2]      = xh0;
      sh_x[nxt][mg * XSTR_ + cg * 2 + 1]  = xh1;
      sh_xl[nxt][mg * XSTR_ + cg * 2]     = __float2bfloat16(xv.x - __bfloat162float(xh0));
      sh_xl[nxt][mg * XSTR_ + cg * 2 + 1] = __float2bfloat16(xv.y - __bfloat162float(xh1));
      // cross-barrier ring refill for next step
#pragma unroll
      for (int j = 0; j < PD_; ++j) load_enc(j);
    }
    __syncthreads();
    cur = nxt;
  }

  // encoder epilogue: store hs[127] + A/C dots for idx 127 from [cur]
  {
    uint4 hv = *(const uint4*)&sh_h[cur][mg * HSTR_ + cg * 8];
    *(uint4*)&hs[((size_t)(b0 + mg) * T_ + (T_ - 1)) * H_ + cg * 8] = hv;
    const float* hp = &s_hf[cur][mg * FSTR_ + cg * 8];
    float pa = 0.f, pc = 0.f;
#pragma unroll
    for (int j = 0; j < 8; ++j) {
      float hvf = hp[j];
      pa += hvf * s_wq[cg * 8 + j];
      pc += hvf * s_bq[cg * 8 + j];
    }
#pragma unroll
    for (int off = 16; off >= 1; off >>= 1) {
      pa += __shfl_xor(pa, off, 64);
      pc += __shfl_xor(pc, off, 64);
    }
    if (cg == 0) {
      s_A[mg * T_ + (T_ - 1)] = pa;
      s_C[mg * T_ + (T_ - 1)] = pc;
    }
  }

  // ============================ DECODER: 32 steps ============================
  float prevr = x[((size_t)(b0 + mg) * T_ + (T_ - 1)) * F_];  // per-group prev
  if (tid < BT_)
    s_prev[tid] = x[((size_t)(b0 + tid) * T_ + (T_ - 1)) * F_];
  __syncthreads();

  for (int s = 0; s < OUT_; ++s) {
    // P1: scores = (prev*A + C)*scale, softmax over T per batch row -> s_scr
    // (prev from register; writes/reads are same-32-lane-group -> no barrier)
    {
      float4 a4 = *(const float4*)(s_A + mg * T_ + cg * 4);
      float4 c4 = *(const float4*)(s_C + mg * T_ + cg * 4);
      const float pv = prevr;
      float sc0 = (pv * a4.x + c4.x) * 0.0625f;
      float sc1 = (pv * a4.y + c4.y) * 0.0625f;
      float sc2 = (pv * a4.z + c4.z) * 0.0625f;
      float sc3 = (pv * a4.w + c4.w) * 0.0625f;
      float mx = fmaxf(fmaxf(sc0, sc1), fmaxf(sc2, sc3));
#pragma unroll
      for (int off = 16; off >= 1; off >>= 1) mx = fmaxf(mx, __shfl_xor(mx, off, 64));
      float e0 = __expf(sc0 - mx), e1 = __expf(sc1 - mx);
      float e2 = __expf(sc2 - mx), e3 = __expf(sc3 - mx);
      float ss = e0 + e1 + e2 + e3;
#pragma unroll
      for (int off = 16; off >= 1; off >>= 1) ss += __shfl_xor(ss, off, 64);
      const float inv = 1.0f / ss;
      float4 wv = make_float4(e0 * inv, e1 * inv, e2 * inv, e3 * inv);
      *(float4*)&s_scr[mg * SSTR_ + cg * 4] = wv;
    }

    // P2: ctx[m,h] = sum_t w[m,t] * hs[m,t,h]  (fp32 VALU, 8+8 uint4 in
    //     flight) + P3 weight-ring prefetch up front
    {
#pragma unroll
      for (int j = 0; j < PD_; ++j) load_dec(j);

      float acc[8] = {0.f, 0.f, 0.f, 0.f, 0.f, 0.f, 0.f, 0.f};
      const __hip_bfloat16* hp = hs + (size_t)(b0 + mg) * T_ * H_ + cg * 8;
      const float* wp = &s_scr[mg * SSTR_];
      uint4 bA[8], bB[8];
#pragma unroll
      for (int u = 0; u < 8; ++u) bA[u] = *(const uint4*)(hp + (size_t)u * H_);
      auto p2fma = [&](const uint4& hv, float wt) {
        acc[0] = fmaf(wt, __uint_as_float(hv.x << 16),         acc[0]);
        acc[1] = fmaf(wt, __uint_as_float(hv.x & 0xFFFF0000u), acc[1]);
        acc[2] = fmaf(wt, __uint_as_float(hv.y << 16),         acc[2]);
        acc[3] = fmaf(wt, __uint_as_float(hv.y & 0xFFFF0000u), acc[3]);
        acc[4] = fmaf(wt, __uint_as_float(hv.z << 16),         acc[4]);
        acc[5] = fmaf(wt, __uint_as_float(hv.z & 0xFFFF0000u), acc[5]);
        acc[6] = fmaf(wt, __uint_as_float(hv.w << 16),         acc[6]);
        acc[7] = fmaf(wt, __uint_as_float(hv.w & 0xFFFF0000u), acc[7]);
      };
      for (int tb = 0; tb < T_; tb += 16) {
#pragma unroll
        for (int u = 0; u < 8; ++u) bB[u] = *(const uint4*)(hp + (size_t)(tb + 8 + u) * H_);
#pragma unroll
        for (int u = 0; u < 8; ++u) p2fma(bA[u], wp[tb + u]);
        if (tb + 16 < T_) {
#pragma unroll
          for (int u = 0; u < 8; ++u) bA[u] = *(const uint4*)(hp + (size_t)(tb + 16 + u) * H_);
        }
#pragma unroll
        for (int u = 0; u < 8; ++u) p2fma(bB[u], wp[tb + 8 + u]);
      }
#pragma unroll
      for (int j = 0; j < 8; ++j) {
        float v = acc[j];
        s_hf[0][mg * FSTR_ + cg * 8 + j] = v;
        __hip_bfloat16 hi = __float2bfloat16(v);
        sh_h[0][mg * HSTR_ + cg * 8 + j] = hi;
        sh_l[0][mg * HSTR_ + cg * 8 + j] = __float2bfloat16(v - __bfloat162float(hi));
      }
    }
    __syncthreads();

    // P3: decoder GRU: gh = ctx @ dWhh^T (MFMA ring); gi = prev*dWih + b
    {
#pragma unroll
      for (int kk = 0; kk < 8; ++kk) {
        ah[kk] = *(const bf16x8*)&sh_h[0][l16 * HSTR_ + kk * 32 + quad * 8];
        al[kk] = *(const bf16x8*)&sh_l[0][l16 * HSTR_ + kk * 32 + quad * 8];
      }
      f32x4 z4 = {0.f, 0.f, 0.f, 0.f};
      f32x4 ar0 = z4, az0 = z4, anh0 = z4;
      f32x4 ar1 = z4, az1 = z4, anh1 = z4;
#pragma unroll
      for (int j = 0; j < 16; ++j) {
        if (j < 8) use_whh(j,     j % PD_, ar0, az0, anh0);
        else       use_whh(j - 8, j % PD_, ar1, az1, anh1);
        if (j + PD_ < 16) load_dec(j + PD_);

        if (j == 7 || j == 15) {
          const int s2 = (j == 7) ? 0 : 1;
          const f32x4& ar = (j == 7) ? ar0 : ar1;
          const f32x4& az = (j == 7) ? az0 : az1;
          const f32x4& anh = (j == 7) ? anh0 : anh1;
          const int g = 16 * (2 * wid + s2) + l16;
          const float dr = s_dbr[g], dz = s_dbz[g], din = s_dbin[g], dhn = s_dbhn[g];
          const float wir = s_dwih[g], wiz = s_dwih[H_ + g], win = s_dwih[2 * H_ + g];
#pragma unroll
          for (int i = 0; i < 4; ++i) {
            const int m = quad * 4 + i;
            const float pv = s_prev[m];
            float r = sigm_(ar[i] + pv * wir + dr);
            float z = sigm_(az[i] + pv * wiz + dz);
            float n = tanh_(pv * win + din + r * (anh[i] + dhn));
            float ctxv = s_hf[0][m * FSTR_ + g];
            float hd = (1.0f - z) * n + z * ctxv;
            __hip_bfloat16 hi = __float2bfloat16(hd);
            sh_h[1][m * HSTR_ + g] = hi;
            sh_l[1][m * HSTR_ + g] = __float2bfloat16(hd - __bfloat162float(hi));
          }
        }
      }
    }
    __syncthreads();

    // P4: fc1 + relu (MFMA ring) -> fp32 in s_scr
    {
#pragma unroll
      for (int kk = 0; kk < 8; ++kk) {
        ah[kk] = *(const bf16x8*)&sh_h[1][l16 * HSTR_ + kk * 32 + quad * 8];  // ad
        al[kk] = *(const bf16x8*)&sh_l[1][l16 * HSTR_ + kk * 32 + quad * 8];  // adl
      }
#pragma unroll
      for (int j = 0; j < PD_; ++j) load_fc(j);
      f32x4 z4 = {0.f, 0.f, 0.f, 0.f};
      f32x4 a10 = z4, a11 = z4;
#pragma unroll
      for (int j = 0; j < 16; ++j) {
        if (j < 8) use_fc(j,     j % PD_, a10);
        else       use_fc(j - 8, j % PD_, a11);
        if (j + PD_ < 16) load_fc(j + PD_);

        if (j == 7 || j == 15) {
          const int s2 = (j == 7) ? 0 : 1;
          const f32x4& a1 = (j == 7) ? a10 : a11;
          const int jcol = 16 * (2 * wid + s2) + l16;
          const float bj = s_f1b[jcol];
#pragma unroll
          for (int i = 0; i < 4; ++i) {
            const int m = quad * 4 + i;
            s_scr[m * SSTR_ + jcol] = fmaxf(a1[i] + bj, 0.0f);
          }
        }
      }
    }
    __syncthreads();

    // P5: fc2 (fp32 dot) -> out, update prev (register + LDS mirror)
    {
      const float* ap = &s_scr[mg * SSTR_ + cg * 8];
      float p = 0.f;
#pragma unroll
      for (int j = 0; j < 8; ++j)
        p += ap[j] * s_f2w[cg * 8 + j];
#pragma unroll
      for (int off = 16; off >= 1; off >>= 1) p += __shfl_xor(p, off, 64);
      float o = p + s_f2b;
      prevr = o;                        // all lanes of group hold the sum
      if (cg == 0) {
        s_prev[mg] = o;                 // for P3's cross-group read
        dout[(size_t)(b0 + mg) * OUT_ + s] = o;
      }
    }
    // no barrier: P1'/P2' touch only same-group rows; next cross-group
    // consumers (P3') are behind the P2'->P3' barrier.
  }
}

extern "C" void kernel_launch(void* const* d_in, const int* in_sizes, int n_in,
                              void* d_out, int out_size, void* d_ws, size_t ws_size,
                              hipStream_t stream) {
  (void)in_sizes; (void)n_in; (void)out_size; (void)ws_size;
  const float* x    = (const float*)d_in[0];
  const float* h0   = (const float*)d_in[1];
  const float* eWih = (const float*)d_in[2];
  const float* eWhh = (const float*)d_in[3];
  const float* ebih = (const float*)d_in[4];
  const float* ebhh = (const float*)d_in[5];
  const float* dWih = (const float*)d_in[6];
  const float* dWhh = (const float*)d_in[7];
  const float* dbih = (const float*)d_in[8];
  const float* dbhh = (const float*)d_in[9];
  const float* aWq  = (const float*)d_in[10];
  const float* abq  = (const float*)d_in[11];
  const float* f1W  = (const float*)d_in[12];
  const float* f1b  = (const float*)d_in[13];
  const float* f2W  = (const float*)d_in[14];
  const float* f2b  = (const float*)d_in[15];

  __hip_bfloat16* hs = (__hip_bfloat16*)d_ws;   // 134,217,728 B
  __hip_bfloat16* wb = (__hip_bfloat16*)((char*)d_ws + (size_t)B_ * T_ * H_ * 2);

  hipLaunchKernelGGL(af_convert_weights, dim3(256), dim3(256), 0, stream,
                     eWih, eWhh, dWhh, f1W, wb);
  hipLaunchKernelGGL(af_fused_kernel, dim3(NB_), dim3(NTH_), 0, stream,
                     x, h0, ebih, ebhh, dWih, dbih, dbhh, aWq, abq, f1b, f2W, f2b,
                     wb + PK_EIH_, wb + PK_EHH_, wb + PK_DHH_, wb + PK_F1_,
                     hs, (float*)d_out);
}